// Round 5
// baseline (2990.378 us; speedup 1.0000x reference)
//
#include <hip/hip_runtime.h>
#include <stdint.h>

// ---------------------------------------------------------------------------
// StageNet forward on MI355X — ROUND 16.
// R15 (2853us): VGPR_Count=64 exposed the unit error — 16-wave blocks cap
// VGPR at 128/lane (512/SIMD file), so "register-resident Wr" silently became
// serialized L2 re-streaming (40us/step). CU capacity (512KB regs + 160KB
// LDS) < Wr 1.19MB -> per-step stream is STRUCTURAL; the floor is per-CU
// L2->CU BW (~150-230GB/s) = 5-8us/step, reachable only with deep pipelined
// prefetch. This round, k_scan4:
//  * 16 blocks x 512 thr (8 waves, VGPR cap 256).
//  * Wr pre-packed into 25 slabs of 4 tiles (49KB), PRE-SWIZZLED global
//    layout (store chunk c = orig chunk c^(r&7)) so linear GLL staging gives
//    conflict-free swizzled ds_read_b128 A-frags (T2 both-sides rule).
//  * Per step: dbuf'd slab pipeline, raw s_barrier + exact vmcnt(0) +
//    sched_barrier(0) (no __syncthreads drain in-loop); GLL(s+1) issued
//    post-barrier, flies during MFMA(s)+fused gates(s). Wave T%8 owns tile
//    T (creg/hreg static idx). All global writes batched at step end.
// Predicted: k_scan4 300-550us; total ~1.1-1.25ms.
// ---------------------------------------------------------------------------

typedef unsigned short u16;
typedef short bf16x8 __attribute__((ext_vector_type(8)));
typedef float f32x4 __attribute__((ext_vector_type(4)));

#define GLL(gp, lp)                                                            \
  __builtin_amdgcn_global_load_lds(                                            \
      (const __attribute__((address_space(1))) unsigned int*)(gp),             \
      (__attribute__((address_space(3))) unsigned int*)(lp), 16, 0, 0)

__device__ __forceinline__ float bf2f(u16 u) {
  union { unsigned int i; float f; } v;
  v.i = ((unsigned int)u) << 16;
  return v.f;
}
__device__ __forceinline__ u16 f2bf(float f) {
  union { float f; unsigned int i; } v;
  v.f = f;
  unsigned int r = (v.i + 0x7fffu + ((v.i >> 16) & 1u)) >> 16;
  return (u16)r;
}
__device__ __forceinline__ float ldf(const void* p, size_t i, int isbf) {
  return isbf ? bf2f(((const u16*)p)[i]) : ((const float*)p)[i];
}
__device__ __forceinline__ float sigf(float x) { return 1.f / (1.f + __expf(-x)); }
__device__ __forceinline__ float tanhf_(float x) {
  float cx = fminf(fmaxf(x, -15.f), 15.f);
  float e = __expf(2.f * cx);
  return (e - 1.f) / (e + 1.f);
}
__device__ __forceinline__ float dot8_bf(const u16* w, const float* lp) {
  uint4 wv = *(const uint4*)w;
  union { unsigned int u; float f; } a0, a1;
  float s;
  a0.u = wv.x << 16; a1.u = wv.x & 0xffff0000u;
  s = lp[0] * a0.f + lp[1] * a1.f;
  a0.u = wv.y << 16; a1.u = wv.y & 0xffff0000u;
  s += lp[2] * a0.f + lp[3] * a1.f;
  a0.u = wv.z << 16; a1.u = wv.z & 0xffff0000u;
  s += lp[4] * a0.f + lp[5] * a1.f;
  a0.u = wv.w << 16; a1.u = wv.w & 0xffff0000u;
  s += lp[6] * a0.f + lp[7] * a1.f;
  return s;
}

// ------------------------- dtype detection (safety) ------------------------
__global__ void k_detect(const unsigned int* __restrict__ emb_raw,
                         int* __restrict__ flag) {
  if (blockIdx.x == 0 && threadIdx.x == 0) {
    int cnt = 0;
    for (int i = 64; i < 128; ++i) {
      unsigned int u = emb_raw[i];
      unsigned int lo = u & 0xffffu;
      unsigned int ex = (lo >> 7) & 0xffu;
      if (lo != 0 && ex >= 100 && ex <= 126) ++cnt;
    }
    *flag = (cnt >= 32) ? 1 : 0;
  }
}

// ------------------------- canonicalization --------------------------------
__global__ void k_cvt_emb(const void* __restrict__ src, u16* __restrict__ dst,
                          const int* __restrict__ flagp) {
  int isbf = *flagp;
  int n = 10001 * 128;
  int i = blockIdx.x * blockDim.x + threadIdx.x;
  int stride = gridDim.x * blockDim.x;
  for (; i < n; i += stride)
    dst[i] = isbf ? ((const u16*)src)[i] : f2bf(((const float*)src)[i]);
}

__global__ void k_repack_wk(const void* __restrict__ wk, u16* __restrict__ wkp,
                            const int* __restrict__ flagp) {
  int isbf = *flagp;
  size_t i = (size_t)blockIdx.x * blockDim.x + threadIdx.x;
  size_t total = (size_t)1664 * 8192;
  size_t stride = (size_t)gridDim.x * blockDim.x;
  for (; i < total; i += stride) {
    size_t g = i >> 13, k = i & 8191;
    wkp[i] = (g < 1552) ? f2bf(ldf(wk, g * 8193 + k, isbf)) : (u16)0;
  }
}

// wrP3: slab-packed + swizzled Wr for k_scan4.
// Layout: [100 tiles][16 rows][48 chunks of 8 u16]; tile T row r stored chunk
// c holds ORIGINAL k-chunk (c ^ (r&7)) of permuted row g' = 16T + r.
// g' permutation: g'<16 -> g'=g ; g'=16+4h+q <-> g = 16+q*384+h. Tiles 97..99
// are zero pads. Also emits biasC, wlC.
__global__ void k_prep_wr3(const void* __restrict__ wr, const void* __restrict__ wk,
                           const void* __restrict__ bk, const void* __restrict__ br,
                           u16* __restrict__ wrP3, float* __restrict__ biasC,
                           float* __restrict__ wlC, const int* __restrict__ flagp) {
  int isbf = *flagp;
  int i0 = blockIdx.x * blockDim.x + threadIdx.x;
  int stride = gridDim.x * blockDim.x;
  for (int j = i0; j < 100 * 16 * 384; j += stride) {
    int T = j / 6144;
    int rem = j - T * 6144;
    int r = rem / 384;
    int k = rem - r * 384;
    int chunk = k >> 3, kin = k & 7;
    int korig = ((chunk ^ (r & 7)) << 3) + kin;
    int gp = T * 16 + r;
    u16 val = (u16)0;
    if (gp < 1552) {
      int g;
      if (gp < 16) g = gp;
      else {
        int rr = gp - 16;
        int q = rr & 3, h = rr >> 2;
        g = 16 + q * 384 + h;
      }
      val = f2bf(ldf(wr, (size_t)g * 385 + korig, isbf));
    }
    wrP3[j] = val;
  }
  for (int g = i0; g < 1552; g += stride) {
    biasC[g] = ldf(bk, g, isbf) + ldf(br, g, isbf);
    wlC[g] = ldf(wk, (size_t)g * 8193 + 8192, isbf) + ldf(wr, g * 385 + 384, isbf);
  }
}

__global__ void k_repack_wc(const void* __restrict__ wc, u16* __restrict__ wcp,
                            const int* __restrict__ flagp) {
  int isbf = *flagp;
  int i0 = blockIdx.x * blockDim.x + threadIdx.x;
  int stride = gridDim.x * blockDim.x;
  for (int j = i0; j < 384 * 3840; j += stride) {
    int o = j / 3840;
    int r = j - o * 3840;
    int k = r / 384;
    int h = r - k * 384;
    wcp[j] = f2bf(ldf(wc, (o * 384 + h) * 10 + k, isbf));  // [o][h][k]->[o][k][h]
  }
}

// canonical fp32: [vt 12800][Ws 24576][bs 64][Wrs 24576][brs 384][bc 384]
//                 [Wo 49152][bo 128]  (total 112064 floats)
__global__ void k_cvt_smalls(const void* vt, const void* Ws, const void* bs,
                             const void* Wrs, const void* brs, const void* bc,
                             const void* Wo, const void* bo,
                             float* __restrict__ dst, const int* __restrict__ flagp) {
  int isbf = *flagp;
  int i = blockIdx.x * blockDim.x + threadIdx.x;
  int stride = gridDim.x * blockDim.x;
  for (; i < 112064; i += stride) {
    float v;
    if (i < 12800) v = ldf(vt, i, isbf);
    else if (i < 37376) v = ldf(Ws, i - 12800, isbf);
    else if (i < 37440) v = ldf(bs, i - 37376, isbf);
    else if (i < 62016) v = ldf(Wrs, i - 37440, isbf);
    else if (i < 62400) v = ldf(brs, i - 62016, isbf);
    else if (i < 62784) v = ldf(bc, i - 62400, isbf);
    else if (i < 111936) v = ldf(Wo, i - 62784, isbf);
    else v = ldf(bo, i - 111936, isbf);
    dst[i] = v;
  }
}

// ------------------------- PH1: gathered GEMM, swizzled GLL staging --------
// grid (100 m-tiles, 13 g-tiles) — m FAST so each Wk g-panel stays L2/LLC-hot.
// Tile 128x128, BK=64 bf16. Epilogue writes XKb permuted-transposed [t][b][g'].
__global__ __launch_bounds__(256) void k_gemm_xk(
    const int* __restrict__ node_ids, const u16* __restrict__ embB,
    const u16* __restrict__ wkp, const float* __restrict__ vtF,
    const float* __restrict__ biasC, const float* __restrict__ wlC,
    u16* __restrict__ xkb) {
  __shared__ alignas(16) u16 As[128 * 64];
  __shared__ alignas(16) u16 Bs[128 * 64];
  int tid = threadIdx.x;
  int m0 = blockIdx.x * 128;
  int g0 = blockIdx.y * 128;
  int lane = tid & 63, w = tid >> 6;
  int wy = w >> 1, wx = w & 1;
  f32x4 acc[4][4];
#pragma unroll
  for (int i = 0; i < 4; ++i)
#pragma unroll
    for (int j = 0; j < 4; ++j) acc[i][j] = (f32x4){0.f, 0.f, 0.f, 0.f};

  int l15 = lane & 15, lq = lane >> 4;
  int lr = lane >> 3, lc = lane & 7;  // row-in-chunk, 16B-chunk slot
  int swc = (lc ^ lr) * 8;            // swizzled global chunk offset (u16)
  int cRd = (lq ^ (l15 & 7)) * 8;     // swizzled read chunk, ks=0 (u16)

  for (int kt = 0; kt < 128; ++kt) {
    __syncthreads();
    // ---- stage A (gathered embed rows), swizzled global chunk
#pragma unroll
    for (int c = 0; c < 4; ++c) {
      int chunk = w * 4 + c;
      int r = chunk * 8 + lr;
      int id = node_ids[(size_t)(m0 + r) * 64 + (kt >> 1)];
      const u16* gp = embB + (size_t)id * 128 + (kt & 1) * 64 + swc;
      u16* lp = As + chunk * 512 + lane * 8;
      GLL(gp, lp);
    }
    // ---- stage B (Wk tile), swizzled global chunk
#pragma unroll
    for (int c = 0; c < 4; ++c) {
      int chunk = w * 4 + c;
      int r = chunk * 8 + lr;
      const u16* gp = wkp + (size_t)(g0 + r) * 8192 + (size_t)kt * 64 + swc;
      u16* lp = Bs + chunk * 512 + lane * 8;
      GLL(gp, lp);
    }
    __syncthreads();
    const u16* Ab = As + (wy * 64 + l15) * 64;
    const u16* Bb = Bs + (wx * 64 + l15) * 64;
#pragma unroll
    for (int ks = 0; ks < 2; ++ks) {
      int co = cRd ^ (ks * 32);
      bf16x8 av[4], bv[4];
#pragma unroll
      for (int i = 0; i < 4; ++i) av[i] = *(const bf16x8*)(Ab + i * 1024 + co);
#pragma unroll
      for (int j = 0; j < 4; ++j) bv[j] = *(const bf16x8*)(Bb + j * 1024 + co);
#pragma unroll
      for (int i = 0; i < 4; ++i)
#pragma unroll
        for (int j = 0; j < 4; ++j)
          acc[i][j] =
              __builtin_amdgcn_mfma_f32_16x16x32_bf16(av[i], bv[j], acc[i][j], 0, 0, 0);
    }
  }
  float vt[4][4];
#pragma unroll
  for (int i = 0; i < 4; ++i)
#pragma unroll
    for (int p = 0; p < 4; ++p)
      vt[i][p] = vtF[m0 + wy * 64 + i * 16 + lq * 4 + p];
#pragma unroll
  for (int j = 0; j < 4; ++j) {
    int gcol = g0 + wx * 64 + j * 16 + l15;
    if (gcol < 1552) {
      float bC = biasC[gcol], wC = wlC[gcol];
      int gp;
      if (gcol < 16) gp = gcol;
      else {
        int r = gcol - 16;
        int h = r % 384, q = r / 384;
        gp = 16 + h * 4 + q;
      }
#pragma unroll
      for (int i = 0; i < 4; ++i)
#pragma unroll
        for (int p = 0; p < 4; ++p) {
          int grow = m0 + wy * 64 + i * 16 + lq * 4 + p;
          int b = grow / 50, t = grow - b * 50;
          xkb[((size_t)t * 256 + b) * 1552 + gp] =
              f2bf(acc[i][j][p] + bC + vt[i][p] * wC);
        }
    }
  }
}

// ------------------------- PH2: pipelined-stream scan ----------------------
// 16 self-contained blocks x 512 thr (8 waves). Wr streamed from wrP3 (L2-
// resident, same 1.2MB every step) through a 2x49KB LDS slab double-buffer
// via GLL; raw s_barrier + exact vmcnt(0) (no vmem ops inside the slab loop;
// all global writes batched at step end). Wave T%8 owns tile T: MFMA D-frag
// = 4 gate pre-acts of (b=b0+l15, h=4(T-1)+lq); gates in-register.
__global__ __launch_bounds__(512, 2) void k_scan4(
    const u16* __restrict__ xkb,   // [50][256][1552] bf16, permuted g'
    const u16* __restrict__ wrP3,  // [100][16][384] bf16, slab-packed swizzled
    float* __restrict__ hbuf,      // [50][256][384] f32
    float* __restrict__ dbuf) {    // [50][256] f32
  __shared__ alignas(16) u16 bufA[4 * 6144];  // 49152B
  __shared__ alignas(16) u16 bufB[4 * 6144];  // 49152B
  __shared__ alignas(16) u16 hS[16 * 392];    // 12544B
  __shared__ alignas(16) float fmTile[16 * 17];
  __shared__ float fmS[16][8], imS[16][8];

  int tid = threadIdx.x;
  int b0 = blockIdx.x * 16;
  int w = tid >> 6, lane = tid & 63, l15 = lane & 15, lq = lane >> 4;
  int swz = l15 & 7;

  for (int i = tid; i < 16 * 392; i += 512) hS[i] = 0;

  float creg[13];
#pragma unroll
  for (int i = 0; i < 13; ++i) creg[i] = 0.f;

  // prologue: issue slab 0 -> bufA (6 GLL per wave; chunk = w*6+jj of 1KB)
#define ISSUE_SLAB(SL, BUFP)                                                   \
  {                                                                            \
    const u16* sb_ = wrP3 + (size_t)(SL) * 24576 + (w * 6) * 512 + lane * 8;   \
    u16* db_ = (BUFP) + (w * 6) * 512 + lane * 8;                              \
    GLL(sb_ + 0 * 512, db_ + 0 * 512);                                         \
    GLL(sb_ + 1 * 512, db_ + 1 * 512);                                         \
    GLL(sb_ + 2 * 512, db_ + 2 * 512);                                         \
    GLL(sb_ + 3 * 512, db_ + 3 * 512);                                         \
    GLL(sb_ + 4 * 512, db_ + 4 * 512);                                         \
    GLL(sb_ + 5 * 512, db_ + 5 * 512);                                         \
  }

  ISSUE_SLAB(0, bufA);

  for (int t = 0; t < 50; ++t) {
    u16* bufP = (t & 1) ? bufB : bufA;  // parity of slab0 this step
    u16* bufQ = (t & 1) ? bufA : bufB;
    const u16* xkrow = xkb + ((size_t)t * 256 + b0 + l15) * 1552;

    // ---- xk prefetch (gate quads + fm/im row)
    uint2 xkg[13];
#pragma unroll
    for (int i = 0; i < 13; ++i) {
      int T = 8 * i + w;
      if (T >= 1 && T <= 96)
        xkg[i] = *(const uint2*)(xkrow + T * 16 + lq * 4);
      else
        xkg[i] = (uint2){0u, 0u};
    }
    uint4 xksm = (uint4){0u, 0u, 0u, 0u};
    if (tid < 32)
      xksm = *(const uint4*)(xkb + ((size_t)t * 256 + b0 + (tid & 15)) * 1552 +
                             ((tid < 16) ? 0 : 8));

    __syncthreads();  // [A0] slab0 arrived (full drain), prev-step hS writes visible

    // ---- B-frags (h_{t-1})
    bf16x8 hb[12];
#pragma unroll
    for (int ks = 0; ks < 12; ++ks)
      hb[ks] = *(const bf16x8*)(hS + l15 * 392 + ks * 32 + lq * 8);

    ISSUE_SLAB(1, bufQ);

    float hreg[13];
#pragma unroll
    for (int i = 0; i < 13; ++i) hreg[i] = 0.f;
    float dval = 0.f;

    // ---- slab 0 (tiles 0..3): wave j handles tile j
    f32x4 acc0 = (f32x4){0.f, 0.f, 0.f, 0.f};
    if (w < 4) {
      const u16* ab = bufP + w * 6144 + l15 * 384;
#pragma unroll
      for (int ks = 0; ks < 12; ++ks) {
        int c2 = ((ks * 4 + lq) ^ swz) * 8;
        bf16x8 av = *(const bf16x8*)(ab + c2);
        acc0 = __builtin_amdgcn_mfma_f32_16x16x32_bf16(av, hb[ks], acc0, 0, 0, 0);
      }
      if (w == 0) {
#pragma unroll
        for (int p = 0; p < 4; ++p) fmTile[(lq * 4 + p) * 17 + l15] = acc0[p];
      }
    }
    asm volatile("s_waitcnt lgkmcnt(0)" ::: "memory");
    __builtin_amdgcn_s_barrier();  // [B0] fmTile visible
    __builtin_amdgcn_sched_barrier(0);

    // ---- fm/im softmax (fm: tid<16, im: tid 16..31)
    if (tid < 32) {
      int r = tid & 15;
      const u16* xs = (const u16*)&xksm;
      float z[8], m = -1e30f;
#pragma unroll
      for (int j = 0; j < 8; ++j) {
        int jj = (tid < 16) ? j : (8 + j);
        z[j] = fmTile[jj * 17 + r] + bf2f(xs[j]);
        m = fmaxf(m, z[j]);
      }
      float s = 0.f;
#pragma unroll
      for (int j = 0; j < 8; ++j) { z[j] = __expf(z[j] - m); s += z[j]; }
      float inv = 1.f / s;
      if (tid < 16) {
        float run = 0.f, fsum = 0.f;
#pragma unroll
        for (int j = 0; j < 8; ++j) { run += z[j] * inv; fmS[r][j] = run; fsum += run; }
        dval = 1.f - fsum * 0.125f;
      } else {
        float run = 0.f;
#pragma unroll
        for (int j = 7; j >= 0; --j) { run += z[j] * inv; imS[r][j] = run; }
      }
    }
    asm volatile("s_waitcnt lgkmcnt(0)" ::: "memory");
    __builtin_amdgcn_s_barrier();  // [C0] fmS/imS visible
    __builtin_amdgcn_sched_barrier(0);

    // ---- gates for slab-0 tiles 1..3 (waves 1..3; i = 0)
    if (w >= 1 && w < 4) {
      const int i = 0;
      int T = w;
      const u16* xg = (const u16*)&xkg[i];
      float x0 = acc0[0] + bf2f(xg[0]);
      float x1 = acc0[1] + bf2f(xg[1]);
      float x2 = acc0[2] + bf2f(xg[2]);
      float x3 = acc0[3] + bf2f(xg[3]);
      float fg = sigf(x0), ig = sigf(x1), og = sigf(x2), ci = tanhf_(x3);
      int h = 4 * (T - 1) + lq;
      float fm = fmS[l15][0], im = imS[l15][0];  // h<12 -> level 0
      float ov = fm * im;
      float cn = ov * (fg * creg[i] + ig * ci) + (fm - ov) * creg[i] + (im - ov) * ci;
      float hn = og * tanhf_(cn);
      creg[i] = cn;
      hreg[i] = hn;
      hS[l15 * 392 + h] = f2bf(hn);
    }

    // ---- slabs 1..24, fused gates, 1 barrier each
#pragma unroll
    for (int s = 1; s < 25; ++s) {
      asm volatile("s_waitcnt vmcnt(0)" ::: "memory");
      __builtin_amdgcn_s_barrier();
      __builtin_amdgcn_sched_barrier(0);
      u16* nb = ((s + 1) & 1) ? bufQ : bufP;
      if (s < 24) {
        ISSUE_SLAB(s + 1, nb);
      } else {
        if (t != 49) ISSUE_SLAB(0, nb);
      }
      u16* cb = (s & 1) ? bufQ : bufP;
#pragma unroll
      for (int j = 0; j < 4; ++j) {
        const int T = 4 * s + j;
        if (T <= 96) {
          if (w == (T & 7)) {
            const int i = T >> 3;
            const int lvl = (T - 1) / 12;
            f32x4 a = (f32x4){0.f, 0.f, 0.f, 0.f};
            const u16* ab = cb + j * 6144 + l15 * 384;
#pragma unroll
            for (int ks = 0; ks < 12; ++ks) {
              int c2 = ((ks * 4 + lq) ^ swz) * 8;
              bf16x8 av = *(const bf16x8*)(ab + c2);
              a = __builtin_amdgcn_mfma_f32_16x16x32_bf16(av, hb[ks], a, 0, 0, 0);
            }
            const u16* xg = (const u16*)&xkg[i];
            float x0 = a[0] + bf2f(xg[0]);
            float x1 = a[1] + bf2f(xg[1]);
            float x2 = a[2] + bf2f(xg[2]);
            float x3 = a[3] + bf2f(xg[3]);
            float fg = sigf(x0), ig = sigf(x1), og = sigf(x2), ci = tanhf_(x3);
            int h = 4 * (T - 1) + lq;
            float fm = fmS[l15][lvl], im = imS[l15][lvl];
            float ov = fm * im;
            float cn =
                ov * (fg * creg[i] + ig * ci) + (fm - ov) * creg[i] + (im - ov) * ci;
            float hn = og * tanhf_(cn);
            creg[i] = cn;
            hreg[i] = hn;
            hS[l15 * 392 + h] = f2bf(hn);
          }
        }
      }
    }

    // ---- step end: batched global writes (outstanding across step boundary;
    // drained by next step's __syncthreads)
    float* hrow = hbuf + ((size_t)t * 256 + b0 + l15) * 384;
#pragma unroll
    for (int i = 0; i < 13; ++i) {
      int T = 8 * i + w;
      if (T >= 1 && T <= 96) hrow[4 * (T - 1) + lq] = hreg[i];
    }
    if (tid < 16) dbuf[(size_t)t * 256 + b0 + tid] = dval;
  }
#undef ISSUE_SLAB
}

// ------------------------- PH3: final (theme/conv/out) ---------------------
__global__ __launch_bounds__(384) void k_final(
    const float* __restrict__ hbuf, const float* __restrict__ dbuf,
    const unsigned char* __restrict__ am, const float* __restrict__ smalls,
    const u16* __restrict__ wcp, float* __restrict__ out) {
  const float* WsF = smalls + 12800;
  const float* bsF = smalls + 37376;
  const float* WrsF = smalls + 37440;
  const float* brsF = smalls + 62016;
  const float* bcF = smalls + 62400;
  const float* WoF = smalls + 62784;
  const float* boF = smalls + 111936;
  __shared__ alignas(16) float lh2[10][384];
  __shared__ alignas(16) float ti[384];
  __shared__ alignas(16) float us[64];
  __shared__ alignas(16) float rnnS[384];
  __shared__ alignas(16) float hlastS[384];
  __shared__ float ldS[10];
  __shared__ int npad[50];
  __shared__ int lastS;
  int tid = threadIdx.x;
  int b = blockIdx.x;

  if (tid < 50) {
    const unsigned char* mr = am + ((size_t)b * 50 + tid) * 64;
    int all1 = 1;
    for (int q = 0; q < 64; ++q) all1 &= (mr[q] != 0);
    npad[tid] = all1 ? 0 : 1;
  }
  __syncthreads();
  if (tid == 0) {
    int c = 0;
    for (int v = 0; v < 50; ++v) c += npad[v];
    int lv = c - 1;
    int last = lv < 0 ? 0 : lv;
    lastS = last;
    float cum = 0.f, cv[10];
    for (int k = 0; k < 10; ++k) {
      int s = last - 9 + k;
      float dk = (s >= 0) ? dbuf[(size_t)s * 256 + b] : 0.f;
      cum += dk;
      cv[k] = cum;
    }
    float m = cv[0];
    for (int k = 1; k < 10; ++k) m = fmaxf(m, cv[k]);
    float ssum = 0.f, ee[10];
    for (int k = 0; k < 10; ++k) { ee[k] = __expf(cv[k] - m); ssum += ee[k]; }
    float inv = 1.f / ssum;
    for (int k = 0; k < 10; ++k) ldS[k] = ee[k] * inv;
  }
  __syncthreads();
  {  // local_h, theme input, h_last
    int h = tid;
    int last = lastS;
    float ssum = 0.f;
    for (int k = 0; k < 10; ++k) {
      int s = last - 9 + k;
      float hv = (s >= 0) ? hbuf[((size_t)s * 256 + b) * 384 + h] : 0.f;
      float v = hv * ldS[k];
      lh2[k][h] = v;
      ssum += v;
    }
    ti[h] = ssum * 0.1f;
    hlastS[h] = hbuf[((size_t)last * 256 + b) * 384 + h];
  }
  __syncthreads();
  if (tid < 64) {  // u = relu(ti @ Ws^T + bs)
    float a = bsF[tid];
    const float* wr = WsF + (size_t)tid * 384;
    for (int h = 0; h < 384; ++h) a += wr[h] * ti[h];
    us[tid] = fmaxf(a, 0.f);
  }
  __syncthreads();
  {  // theme = sigmoid(u @ Wrs^T + brs); conv; rnn = theme*conv + h_last
    int o = tid;
    float th = brsF[o];
    const float* wr = WrsF + (size_t)o * 64;
    for (int k = 0; k < 64; ++k) th += wr[k] * us[k];
    th = sigf(th);
    float cacc = bcF[o];
    for (int k = 0; k < 10; ++k) {
      const u16* wrow = wcp + ((size_t)o * 10 + k) * 384;
      const float* lrow = lh2[k];
      for (int h8 = 0; h8 < 48; ++h8) cacc += dot8_bf(wrow + h8 * 8, lrow + h8 * 8);
    }
    rnnS[o] = th * cacc + hlastS[o];
  }
  __syncthreads();
  if (tid < 128) {  // out = rnn @ Wo^T + bo, fp32
    float a = boF[tid];
    const float* wr = WoF + (size_t)tid * 384;
    for (int h = 0; h < 384; ++h) a += wr[h] * rnnS[h];
    out[(size_t)b * 128 + tid] = a;
  }
}

// ------------------------- launch ------------------------------------------
extern "C" void kernel_launch(void* const* d_in, const int* in_sizes, int n_in,
                              void* d_out, int out_size, void* d_ws, size_t ws_size,
                              hipStream_t stream) {
  const int* node_ids = (const int*)d_in[0];
  const void* vtR = d_in[3];
  const unsigned char* am = (const unsigned char*)d_in[5];
  const void* embR = d_in[6];
  const void* WkR = d_in[7];
  const void* bkR = d_in[8];
  const void* WrR = d_in[9];
  const void* brR = d_in[10];
  const void* WsR = d_in[11];
  const void* bsR = d_in[12];
  const void* WrsR = d_in[13];
  const void* brsR = d_in[14];
  const void* WcR = d_in[15];
  const void* bcR = d_in[16];
  const void* WoR = d_in[17];
  const void* boR = d_in[18];
  (void)in_sizes; (void)n_in; (void)out_size; (void)ws_size;

  char* ws = (char*)d_ws;
  size_t off = 0;
  auto alloc = [&](size_t bytes) {
    void* p = ws + off;
    off = (off + bytes + 255) & ~(size_t)255;
    return p;
  };
  int* flagp = (int*)alloc(4);
  u16* embB = (u16*)alloc((size_t)10001 * 128 * 2);      // 2.56MB
  u16* WkP = (u16*)alloc((size_t)1664 * 8192 * 2);       // 27.3MB
  u16* WrP3 = (u16*)alloc((size_t)100 * 16 * 384 * 2);   // 1.23MB slab-packed
  float* biasC = (float*)alloc(1552 * 4);
  float* wlC = (float*)alloc(1552 * 4);
  float* smalls = (float*)alloc((size_t)112064 * 4);
  u16* XKb = (u16*)alloc((size_t)12800 * 1552 * 2);      // 39.7MB [t][b][g']
  u16* WcP = (u16*)alloc((size_t)384 * 3840 * 2);        // 2.9MB
  float* Hbuf = (float*)alloc((size_t)50 * 256 * 384 * 4);  // 19.7MB
  float* Dbuf = (float*)alloc((size_t)50 * 256 * 4);

  k_detect<<<dim3(1), dim3(64), 0, stream>>>((const unsigned int*)embR, flagp);
  k_cvt_emb<<<dim3(1024), dim3(256), 0, stream>>>(embR, embB, flagp);
  k_repack_wk<<<dim3(2048), dim3(256), 0, stream>>>(WkR, WkP, flagp);
  k_prep_wr3<<<dim3(512), dim3(256), 0, stream>>>(WrR, WkR, bkR, brR, WrP3, biasC,
                                                  wlC, flagp);
  k_repack_wc<<<dim3(512), dim3(256), 0, stream>>>(WcR, WcP, flagp);
  k_cvt_smalls<<<dim3(128), dim3(256), 0, stream>>>(vtR, WsR, bsR, WrsR, brsR,
                                                    bcR, WoR, boR, smalls, flagp);

  k_gemm_xk<<<dim3(100, 13), dim3(256), 0, stream>>>(node_ids, embB, WkP, smalls,
                                                     biasC, wlC, XKb);

  k_scan4<<<dim3(16), dim3(512), 0, stream>>>(XKb, WrP3, Hbuf, Dbuf);

  k_final<<<dim3(256), dim3(384), 0, stream>>>(Hbuf, Dbuf, am, smalls, WcP,
                                               (float*)d_out);
}

// Round 6
// 1175.867 us; speedup vs baseline: 2.5431x; 2.5431x over previous
//
#include <hip/hip_runtime.h>
#include <stdint.h>

// ---------------------------------------------------------------------------
// StageNet forward on MI355X — ROUND 17.
// R16 post-mortem: per-CU VMEM ingest =~16B/cy -> persistent 16-block scan has
// a 32us/step STRUCTURAL floor (1.2MB Wr through one CU/step). R11's
// 50-launch chain was 2x faster (21.5us/step): kernel-launch boundary = free
// grid barrier, Wr stream split across blocks. Its waste was 25x-redundant
// gates, not launches.
// This round: k_step2 relaunched per t, grid (12 gs x 16 bg) = 192 blocks:
//  * each block: 128 permuted g'-rows x 16 b-rows; streams 110KB Wr slice
//    (L2-hot) + 12KB h + xk/c; MFMA A=Wr,B=h -> lane owns the 4 gate
//    pre-acts of one (b,h); gates in-register; c-state in global f32
//    (same lane every launch); h via double-buffered global bf16.
//  * fm/im tile computed REDUNDANTLY per block (kills intra-step deps).
//  * NO atomics, NO fences — launch boundary is the sync (R11-proven).
// Predicted: chain ~300-450us, total ~1.05-1.3ms.
// ---------------------------------------------------------------------------

typedef unsigned short u16;
typedef short bf16x8 __attribute__((ext_vector_type(8)));
typedef float f32x4 __attribute__((ext_vector_type(4)));

#define GLL(gp, lp)                                                            \
  __builtin_amdgcn_global_load_lds(                                            \
      (const __attribute__((address_space(1))) unsigned int*)(gp),             \
      (__attribute__((address_space(3))) unsigned int*)(lp), 16, 0, 0)

__device__ __forceinline__ float bf2f(u16 u) {
  union { unsigned int i; float f; } v;
  v.i = ((unsigned int)u) << 16;
  return v.f;
}
__device__ __forceinline__ u16 f2bf(float f) {
  union { float f; unsigned int i; } v;
  v.f = f;
  unsigned int r = (v.i + 0x7fffu + ((v.i >> 16) & 1u)) >> 16;
  return (u16)r;
}
__device__ __forceinline__ float ldf(const void* p, size_t i, int isbf) {
  return isbf ? bf2f(((const u16*)p)[i]) : ((const float*)p)[i];
}
__device__ __forceinline__ float sigf(float x) { return 1.f / (1.f + __expf(-x)); }
__device__ __forceinline__ float tanhf_(float x) {
  float cx = fminf(fmaxf(x, -15.f), 15.f);
  float e = __expf(2.f * cx);
  return (e - 1.f) / (e + 1.f);
}
__device__ __forceinline__ float dot8_bf(const u16* w, const float* lp) {
  uint4 wv = *(const uint4*)w;
  union { unsigned int u; float f; } a0, a1;
  float s;
  a0.u = wv.x << 16; a1.u = wv.x & 0xffff0000u;
  s = lp[0] * a0.f + lp[1] * a1.f;
  a0.u = wv.y << 16; a1.u = wv.y & 0xffff0000u;
  s += lp[2] * a0.f + lp[3] * a1.f;
  a0.u = wv.z << 16; a1.u = wv.z & 0xffff0000u;
  s += lp[4] * a0.f + lp[5] * a1.f;
  a0.u = wv.w << 16; a1.u = wv.w & 0xffff0000u;
  s += lp[6] * a0.f + lp[7] * a1.f;
  return s;
}

// ------------------------- dtype detection (safety) ------------------------
__global__ void k_detect(const unsigned int* __restrict__ emb_raw,
                         int* __restrict__ flag) {
  if (blockIdx.x == 0 && threadIdx.x == 0) {
    int cnt = 0;
    for (int i = 64; i < 128; ++i) {
      unsigned int u = emb_raw[i];
      unsigned int lo = u & 0xffffu;
      unsigned int ex = (lo >> 7) & 0xffu;
      if (lo != 0 && ex >= 100 && ex <= 126) ++cnt;
    }
    *flag = (cnt >= 32) ? 1 : 0;
  }
}

// ------------------------- canonicalization --------------------------------
__global__ void k_cvt_emb(const void* __restrict__ src, u16* __restrict__ dst,
                          const int* __restrict__ flagp) {
  int isbf = *flagp;
  int n = 10001 * 128;
  int i = blockIdx.x * blockDim.x + threadIdx.x;
  int stride = gridDim.x * blockDim.x;
  for (; i < n; i += stride)
    dst[i] = isbf ? ((const u16*)src)[i] : f2bf(((const float*)src)[i]);
}

__global__ void k_repack_wk(const void* __restrict__ wk, u16* __restrict__ wkp,
                            const int* __restrict__ flagp) {
  int isbf = *flagp;
  size_t i = (size_t)blockIdx.x * blockDim.x + threadIdx.x;
  size_t total = (size_t)1664 * 8192;
  size_t stride = (size_t)gridDim.x * blockDim.x;
  for (; i < total; i += stride) {
    size_t g = i >> 13, k = i & 8191;
    wkp[i] = (g < 1552) ? f2bf(ldf(wk, g * 8193 + k, isbf)) : (u16)0;
  }
}

// wrP2[g'][k] bf16 (permuted g'): g'<16 -> g'=g ; else g'=16+4h+q <-> g=16+q*384+h
__global__ void k_prep_wr2(const void* __restrict__ wr, const void* __restrict__ wk,
                           const void* __restrict__ bk, const void* __restrict__ br,
                           u16* __restrict__ wrP2, float* __restrict__ biasC,
                           float* __restrict__ wlC, const int* __restrict__ flagp) {
  int isbf = *flagp;
  int i0 = blockIdx.x * blockDim.x + threadIdx.x;
  int stride = gridDim.x * blockDim.x;
  for (int j = i0; j < 1552 * 384; j += stride) {
    int gp = j / 384, k = j - gp * 384;
    int g;
    if (gp < 16) g = gp;
    else {
      int r = gp - 16;
      int q = r & 3, h = r >> 2;
      g = 16 + q * 384 + h;
    }
    wrP2[j] = f2bf(ldf(wr, (size_t)g * 385 + k, isbf));
  }
  for (int g = i0; g < 1552; g += stride) {
    biasC[g] = ldf(bk, g, isbf) + ldf(br, g, isbf);
    wlC[g] = ldf(wk, (size_t)g * 8193 + 8192, isbf) + ldf(wr, g * 385 + 384, isbf);
  }
}

__global__ void k_repack_wc(const void* __restrict__ wc, u16* __restrict__ wcp,
                            const int* __restrict__ flagp) {
  int isbf = *flagp;
  int i0 = blockIdx.x * blockDim.x + threadIdx.x;
  int stride = gridDim.x * blockDim.x;
  for (int j = i0; j < 384 * 3840; j += stride) {
    int o = j / 3840;
    int r = j - o * 3840;
    int k = r / 384;
    int h = r - k * 384;
    wcp[j] = f2bf(ldf(wc, (o * 384 + h) * 10 + k, isbf));  // [o][h][k]->[o][k][h]
  }
}

// canonical fp32: [vt 12800][Ws 24576][bs 64][Wrs 24576][brs 384][bc 384]
//                 [Wo 49152][bo 128]  (total 112064 floats)
__global__ void k_cvt_smalls(const void* vt, const void* Ws, const void* bs,
                             const void* Wrs, const void* brs, const void* bc,
                             const void* Wo, const void* bo,
                             float* __restrict__ dst, const int* __restrict__ flagp) {
  int isbf = *flagp;
  int i = blockIdx.x * blockDim.x + threadIdx.x;
  int stride = gridDim.x * blockDim.x;
  for (; i < 112064; i += stride) {
    float v;
    if (i < 12800) v = ldf(vt, i, isbf);
    else if (i < 37376) v = ldf(Ws, i - 12800, isbf);
    else if (i < 37440) v = ldf(bs, i - 37376, isbf);
    else if (i < 62016) v = ldf(Wrs, i - 37440, isbf);
    else if (i < 62400) v = ldf(brs, i - 62016, isbf);
    else if (i < 62784) v = ldf(bc, i - 62400, isbf);
    else if (i < 111936) v = ldf(Wo, i - 62784, isbf);
    else v = ldf(bo, i - 111936, isbf);
    dst[i] = v;
  }
}

__global__ void k_zero(float* __restrict__ p, int n) {
  int i = blockIdx.x * blockDim.x + threadIdx.x;
  int stride = gridDim.x * blockDim.x;
  for (; i < n; i += stride) p[i] = 0.f;
}

// ------------------------- PH1: gathered GEMM, swizzled GLL staging --------
// grid (100 m-tiles, 13 g-tiles) — m FAST so each Wk g-panel stays L2/LLC-hot.
// Tile 128x128, BK=64 bf16. Epilogue writes XKb permuted-transposed [t][b][g'].
__global__ __launch_bounds__(256) void k_gemm_xk(
    const int* __restrict__ node_ids, const u16* __restrict__ embB,
    const u16* __restrict__ wkp, const float* __restrict__ vtF,
    const float* __restrict__ biasC, const float* __restrict__ wlC,
    u16* __restrict__ xkb) {
  __shared__ alignas(16) u16 As[128 * 64];
  __shared__ alignas(16) u16 Bs[128 * 64];
  int tid = threadIdx.x;
  int m0 = blockIdx.x * 128;
  int g0 = blockIdx.y * 128;
  int lane = tid & 63, w = tid >> 6;
  int wy = w >> 1, wx = w & 1;
  f32x4 acc[4][4];
#pragma unroll
  for (int i = 0; i < 4; ++i)
#pragma unroll
    for (int j = 0; j < 4; ++j) acc[i][j] = (f32x4){0.f, 0.f, 0.f, 0.f};

  int l15 = lane & 15, lq = lane >> 4;
  int lr = lane >> 3, lc = lane & 7;  // row-in-chunk, 16B-chunk slot
  int swc = (lc ^ lr) * 8;            // swizzled global chunk offset (u16)
  int cRd = (lq ^ (l15 & 7)) * 8;     // swizzled read chunk, ks=0 (u16)

  for (int kt = 0; kt < 128; ++kt) {
    __syncthreads();
    // ---- stage A (gathered embed rows), swizzled global chunk
#pragma unroll
    for (int c = 0; c < 4; ++c) {
      int chunk = w * 4 + c;
      int r = chunk * 8 + lr;
      int id = node_ids[(size_t)(m0 + r) * 64 + (kt >> 1)];
      const u16* gp = embB + (size_t)id * 128 + (kt & 1) * 64 + swc;
      u16* lp = As + chunk * 512 + lane * 8;
      GLL(gp, lp);
    }
    // ---- stage B (Wk tile), swizzled global chunk
#pragma unroll
    for (int c = 0; c < 4; ++c) {
      int chunk = w * 4 + c;
      int r = chunk * 8 + lr;
      const u16* gp = wkp + (size_t)(g0 + r) * 8192 + (size_t)kt * 64 + swc;
      u16* lp = Bs + chunk * 512 + lane * 8;
      GLL(gp, lp);
    }
    __syncthreads();
    const u16* Ab = As + (wy * 64 + l15) * 64;
    const u16* Bb = Bs + (wx * 64 + l15) * 64;
#pragma unroll
    for (int ks = 0; ks < 2; ++ks) {
      int co = cRd ^ (ks * 32);
      bf16x8 av[4], bv[4];
#pragma unroll
      for (int i = 0; i < 4; ++i) av[i] = *(const bf16x8*)(Ab + i * 1024 + co);
#pragma unroll
      for (int j = 0; j < 4; ++j) bv[j] = *(const bf16x8*)(Bb + j * 1024 + co);
#pragma unroll
      for (int i = 0; i < 4; ++i)
#pragma unroll
        for (int j = 0; j < 4; ++j)
          acc[i][j] =
              __builtin_amdgcn_mfma_f32_16x16x32_bf16(av[i], bv[j], acc[i][j], 0, 0, 0);
    }
  }
  float vt[4][4];
#pragma unroll
  for (int i = 0; i < 4; ++i)
#pragma unroll
    for (int p = 0; p < 4; ++p)
      vt[i][p] = vtF[m0 + wy * 64 + i * 16 + lq * 4 + p];
#pragma unroll
  for (int j = 0; j < 4; ++j) {
    int gcol = g0 + wx * 64 + j * 16 + l15;
    if (gcol < 1552) {
      float bC = biasC[gcol], wC = wlC[gcol];
      int gp;
      if (gcol < 16) gp = gcol;
      else {
        int r = gcol - 16;
        int h = r % 384, q = r / 384;
        gp = 16 + h * 4 + q;
      }
#pragma unroll
      for (int i = 0; i < 4; ++i)
#pragma unroll
        for (int p = 0; p < 4; ++p) {
          int grow = m0 + wy * 64 + i * 16 + lq * 4 + p;
          int b = grow / 50, t = grow - b * 50;
          xkb[((size_t)t * 256 + b) * 1552 + gp] =
              f2bf(acc[i][j][p] + bC + vt[i][p] * wC);
        }
    }
  }
}

// ------------------------- PH2: per-step g-split kernel --------------------
// grid (12 g-slices, 16 b-groups), 512 thr = 8 waves. Launch boundary = sync.
// Block (gs,bg): 128 permuted gate rows [16+gs*128, +128) x 16 b-rows.
// Wave wv -> 16 rows; MFMA A=Wr(global, L2-hot), B=h(LDS); lane's D-frag =
// 4 gate pre-acts of (b=b0+l15, h=gs*32+wv*4+lq). fm/im tile 0 computed
// redundantly by wave 0 of EVERY block (no intra-step cross-block deps).
// c-state: global f32, same lane each launch. h: double-buffered global bf16.
__global__ __launch_bounds__(512) void k_step2(
    const u16* __restrict__ xkb,   // [50][256][1552] bf16, permuted g'
    const u16* __restrict__ wrP2,  // [1552][384] bf16, permuted g'
    float* __restrict__ hbuf,      // [50][256][384] f32
    float* __restrict__ dbuf,      // [50][256] f32
    const u16* __restrict__ hin,   // [256][384] bf16 (h_{t-1})
    u16* __restrict__ hout,        // [256][384] bf16 (h_t)
    float* __restrict__ cst,       // [256][384] f32 (c state)
    int t) {
  __shared__ alignas(16) u16 hS[16 * 400];
  __shared__ alignas(16) float fmTile[16 * 17];
  __shared__ float fmS[16][8], imS[16][8];
  int tid = threadIdx.x;
  int gs = blockIdx.x, b0 = blockIdx.y * 16;
  int wv = tid >> 6, lane = tid & 63, l15 = lane & 15, lq = lane >> 4;

  int hmy = gs * 32 + wv * 4 + lq;  // this lane's h cell
  int bmy = b0 + l15;               // this lane's batch row

  // ---- early global loads (ILP): xk gate quad, softmax row, c state
  uint2 xkg = *(const uint2*)(xkb + ((size_t)t * 256 + bmy) * 1552 + 16 +
                              gs * 128 + wv * 16 + lq * 4);
  uint4 xksm = (uint4){0u, 0u, 0u, 0u};
  if (tid < 32)
    xksm = *(const uint4*)(xkb + ((size_t)t * 256 + b0 + (tid & 15)) * 1552 +
                           ((tid < 16) ? 0 : 8));
  float cv = cst[(size_t)bmy * 384 + hmy];

  // ---- stage h_{t-1} -> LDS (stride 400 u16: 4-way max on b128 reads)
  {
    const u16* hsrc = hin + (size_t)b0 * 384;
    for (int idx = tid; idx < 768; idx += 512) {
      int r = idx / 48, c = idx - r * 48;
      *(uint4*)(hS + r * 400 + c * 8) = *(const uint4*)(hsrc + r * 384 + c * 8);
    }
  }
  __syncthreads();

  // ---- B-frags (h_{t-1})
  bf16x8 hb[12];
#pragma unroll
  for (int ks = 0; ks < 12; ++ks)
    hb[ks] = *(const bf16x8*)(hS + l15 * 400 + ks * 32 + lq * 8);

  // ---- MFMA: gate tile (all waves) + fm/im tile 0 (wave 0)
  int gRow = 16 + gs * 128 + wv * 16 + l15;
  const u16* arow = wrP2 + (size_t)gRow * 384 + lq * 8;
  const u16* arow0 = wrP2 + (size_t)l15 * 384 + lq * 8;
  f32x4 accg = (f32x4){0.f, 0.f, 0.f, 0.f};
  f32x4 accf = (f32x4){0.f, 0.f, 0.f, 0.f};
#pragma unroll
  for (int ks = 0; ks < 12; ++ks) {
    bf16x8 ag = *(const bf16x8*)(arow + ks * 32);
    accg = __builtin_amdgcn_mfma_f32_16x16x32_bf16(ag, hb[ks], accg, 0, 0, 0);
    if (wv == 0) {
      bf16x8 a0 = *(const bf16x8*)(arow0 + ks * 32);
      accf = __builtin_amdgcn_mfma_f32_16x16x32_bf16(a0, hb[ks], accf, 0, 0, 0);
    }
  }
  if (wv == 0) {
#pragma unroll
    for (int p = 0; p < 4; ++p) fmTile[(lq * 4 + p) * 17 + l15] = accf[p];
  }
  __syncthreads();

  // ---- fm/im softmax (fm: tid<16, im: tid 16..31)
  if (tid < 32) {
    int r = tid & 15;
    const u16* xs = (const u16*)&xksm;
    float z[8], m = -1e30f;
#pragma unroll
    for (int j = 0; j < 8; ++j) {
      int jj = (tid < 16) ? j : (8 + j);
      z[j] = fmTile[jj * 17 + r] + bf2f(xs[j]);
      m = fmaxf(m, z[j]);
    }
    float s = 0.f;
#pragma unroll
    for (int j = 0; j < 8; ++j) { z[j] = __expf(z[j] - m); s += z[j]; }
    float inv = 1.f / s;
    if (tid < 16) {
      float run = 0.f, fsum = 0.f;
#pragma unroll
      for (int j = 0; j < 8; ++j) { run += z[j] * inv; fmS[r][j] = run; fsum += run; }
      if (gs == 0) dbuf[(size_t)t * 256 + b0 + r] = 1.f - fsum * 0.125f;
    } else {
      float run = 0.f;
#pragma unroll
      for (int j = 7; j >= 0; --j) { run += z[j] * inv; imS[r][j] = run; }
    }
  }
  __syncthreads();

  // ---- gates, fully in-register (one (b,h) cell per lane)
  {
    int lmy = hmy / 48;
    const u16* xg = (const u16*)&xkg;
    float x0 = accg[0] + bf2f(xg[0]);
    float x1 = accg[1] + bf2f(xg[1]);
    float x2 = accg[2] + bf2f(xg[2]);
    float x3 = accg[3] + bf2f(xg[3]);
    float fg = sigf(x0), ig = sigf(x1), og = sigf(x2), ci = tanhf_(x3);
    float fm = fmS[l15][lmy], im = imS[l15][lmy];
    float ov = fm * im;
    float cn = ov * (fg * cv + ig * ci) + (fm - ov) * cv + (im - ov) * ci;
    float hn = og * tanhf_(cn);
    cst[(size_t)bmy * 384 + hmy] = cn;
    hbuf[((size_t)t * 256 + bmy) * 384 + hmy] = hn;
    hout[(size_t)bmy * 384 + hmy] = f2bf(hn);
  }
}

// ------------------------- PH3: final (theme/conv/out) ---------------------
__global__ __launch_bounds__(384) void k_final(
    const float* __restrict__ hbuf, const float* __restrict__ dbuf,
    const unsigned char* __restrict__ am, const float* __restrict__ smalls,
    const u16* __restrict__ wcp, float* __restrict__ out) {
  const float* WsF = smalls + 12800;
  const float* bsF = smalls + 37376;
  const float* WrsF = smalls + 37440;
  const float* brsF = smalls + 62016;
  const float* bcF = smalls + 62400;
  const float* WoF = smalls + 62784;
  const float* boF = smalls + 111936;
  __shared__ alignas(16) float lh2[10][384];
  __shared__ alignas(16) float ti[384];
  __shared__ alignas(16) float us[64];
  __shared__ alignas(16) float rnnS[384];
  __shared__ alignas(16) float hlastS[384];
  __shared__ float ldS[10];
  __shared__ int npad[50];
  __shared__ int lastS;
  int tid = threadIdx.x;
  int b = blockIdx.x;

  if (tid < 50) {
    const unsigned char* mr = am + ((size_t)b * 50 + tid) * 64;
    int all1 = 1;
    for (int q = 0; q < 64; ++q) all1 &= (mr[q] != 0);
    npad[tid] = all1 ? 0 : 1;
  }
  __syncthreads();
  if (tid == 0) {
    int c = 0;
    for (int v = 0; v < 50; ++v) c += npad[v];
    int lv = c - 1;
    int last = lv < 0 ? 0 : lv;
    lastS = last;
    float cum = 0.f, cv[10];
    for (int k = 0; k < 10; ++k) {
      int s = last - 9 + k;
      float dk = (s >= 0) ? dbuf[(size_t)s * 256 + b] : 0.f;
      cum += dk;
      cv[k] = cum;
    }
    float m = cv[0];
    for (int k = 1; k < 10; ++k) m = fmaxf(m, cv[k]);
    float ssum = 0.f, ee[10];
    for (int k = 0; k < 10; ++k) { ee[k] = __expf(cv[k] - m); ssum += ee[k]; }
    float inv = 1.f / ssum;
    for (int k = 0; k < 10; ++k) ldS[k] = ee[k] * inv;
  }
  __syncthreads();
  {  // local_h, theme input, h_last
    int h = tid;
    int last = lastS;
    float ssum = 0.f;
    for (int k = 0; k < 10; ++k) {
      int s = last - 9 + k;
      float hv = (s >= 0) ? hbuf[((size_t)s * 256 + b) * 384 + h] : 0.f;
      float v = hv * ldS[k];
      lh2[k][h] = v;
      ssum += v;
    }
    ti[h] = ssum * 0.1f;
    hlastS[h] = hbuf[((size_t)last * 256 + b) * 384 + h];
  }
  __syncthreads();
  if (tid < 64) {  // u = relu(ti @ Ws^T + bs)
    float a = bsF[tid];
    const float* wr = WsF + (size_t)tid * 384;
    for (int h = 0; h < 384; ++h) a += wr[h] * ti[h];
    us[tid] = fmaxf(a, 0.f);
  }
  __syncthreads();
  {  // theme = sigmoid(u @ Wrs^T + brs); conv; rnn = theme*conv + h_last
    int o = tid;
    float th = brsF[o];
    const float* wr = WrsF + (size_t)o * 64;
    for (int k = 0; k < 64; ++k) th += wr[k] * us[k];
    th = sigf(th);
    float cacc = bcF[o];
    for (int k = 0; k < 10; ++k) {
      const u16* wrow = wcp + ((size_t)o * 10 + k) * 384;
      const float* lrow = lh2[k];
      for (int h8 = 0; h8 < 48; ++h8) cacc += dot8_bf(wrow + h8 * 8, lrow + h8 * 8);
    }
    rnnS[o] = th * cacc + hlastS[o];
  }
  __syncthreads();
  if (tid < 128) {  // out = rnn @ Wo^T + bo, fp32
    float a = boF[tid];
    const float* wr = WoF + (size_t)tid * 384;
    for (int h = 0; h < 384; ++h) a += wr[h] * rnnS[h];
    out[(size_t)b * 128 + tid] = a;
  }
}

// ------------------------- launch ------------------------------------------
extern "C" void kernel_launch(void* const* d_in, const int* in_sizes, int n_in,
                              void* d_out, int out_size, void* d_ws, size_t ws_size,
                              hipStream_t stream) {
  const int* node_ids = (const int*)d_in[0];
  const void* vtR = d_in[3];
  const unsigned char* am = (const unsigned char*)d_in[5];
  const void* embR = d_in[6];
  const void* WkR = d_in[7];
  const void* bkR = d_in[8];
  const void* WrR = d_in[9];
  const void* brR = d_in[10];
  const void* WsR = d_in[11];
  const void* bsR = d_in[12];
  const void* WrsR = d_in[13];
  const void* brsR = d_in[14];
  const void* WcR = d_in[15];
  const void* bcR = d_in[16];
  const void* WoR = d_in[17];
  const void* boR = d_in[18];
  (void)in_sizes; (void)n_in; (void)out_size; (void)ws_size;

  char* ws = (char*)d_ws;
  size_t off = 0;
  auto alloc = [&](size_t bytes) {
    void* p = ws + off;
    off = (off + bytes + 255) & ~(size_t)255;
    return p;
  };
  int* flagp = (int*)alloc(4);
  u16* embB = (u16*)alloc((size_t)10001 * 128 * 2);      // 2.56MB
  u16* WkP = (u16*)alloc((size_t)1664 * 8192 * 2);       // 27.3MB
  u16* WrP2 = (u16*)alloc((size_t)1552 * 384 * 2);       // 1.19MB bf16 permuted
  float* biasC = (float*)alloc(1552 * 4);
  float* wlC = (float*)alloc(1552 * 4);
  float* smalls = (float*)alloc((size_t)112064 * 4);
  u16* XKb = (u16*)alloc((size_t)12800 * 1552 * 2);      // 39.7MB [t][b][g']
  u16* WcP = (u16*)alloc((size_t)384 * 3840 * 2);        // 2.9MB
  float* Hbuf = (float*)alloc((size_t)50 * 256 * 384 * 4);  // 19.7MB
  float* Dbuf = (float*)alloc((size_t)50 * 256 * 4);
  u16* Hx = (u16*)alloc((size_t)2 * 256 * 384 * 2);      // 393KB
  float* Cst = (float*)alloc((size_t)256 * 384 * 4);     // 393KB

  k_detect<<<dim3(1), dim3(64), 0, stream>>>((const unsigned int*)embR, flagp);
  k_cvt_emb<<<dim3(1024), dim3(256), 0, stream>>>(embR, embB, flagp);
  k_repack_wk<<<dim3(2048), dim3(256), 0, stream>>>(WkR, WkP, flagp);
  k_prep_wr2<<<dim3(512), dim3(256), 0, stream>>>(WrR, WkR, bkR, brR, WrP2, biasC,
                                                  wlC, flagp);
  k_repack_wc<<<dim3(512), dim3(256), 0, stream>>>(WcR, WcP, flagp);
  k_cvt_smalls<<<dim3(128), dim3(256), 0, stream>>>(vtR, WsR, bsR, WrsR, brsR,
                                                    bcR, WoR, boR, smalls, flagp);
  k_zero<<<dim3(96), dim3(256), 0, stream>>>((float*)Hx, 98304);
  k_zero<<<dim3(96), dim3(256), 0, stream>>>(Cst, 98304);

  k_gemm_xk<<<dim3(100, 13), dim3(256), 0, stream>>>(node_ids, embB, WkP, smalls,
                                                     biasC, wlC, XKb);

  for (int t = 0; t < 50; ++t) {
    const u16* hin = Hx + (size_t)(t & 1) * (256 * 384);
    u16* hout = Hx + (size_t)((t + 1) & 1) * (256 * 384);
    k_step2<<<dim3(12, 16), dim3(512), 0, stream>>>(XKb, WrP2, Hbuf, Dbuf, hin,
                                                    hout, Cst, t);
  }

  k_final<<<dim3(256), dim3(384), 0, stream>>>(Hbuf, Dbuf, am, smalls, WcP,
                                               (float*)d_out);
}

// Round 7
// 1153.373 us; speedup vs baseline: 2.5927x; 1.0195x over previous
//
#include <hip/hip_runtime.h>
#include <stdint.h>

// ---------------------------------------------------------------------------
// StageNet forward on MI355X — ROUND 18.
// R17: 1176us (best). Step chain 536us (10.7us/step, launch-bound, OK).
// k_gemm_xk 570us with WRITE 173MB vs 39.7MB output (4.4x amp) + 170MB RMW
// fetch: epilogue's g->g' permutation scatters 16-lane stores stride-4.
// This round: permutation moved into k_repack_wk (Wk rows stored g'-order)
// + GEMM m-remap m' = t*256+b (t const per 128-tile; node_ids/vt gathered
// accordingly). Epilogue now writes g'-contiguous 32B sector-aligned chunks
// (amp ~1x). Math bitwise identical; k_step2/wrP2/XKb layout untouched.
// Predicted: gemm WRITE 173->45MB, FETCH 246->90MB, dur 570->460-510;
// total ~1040-1090us.
// ---------------------------------------------------------------------------

typedef unsigned short u16;
typedef short bf16x8 __attribute__((ext_vector_type(8)));
typedef float f32x4 __attribute__((ext_vector_type(4)));

#define GLL(gp, lp)                                                            \
  __builtin_amdgcn_global_load_lds(                                            \
      (const __attribute__((address_space(1))) unsigned int*)(gp),             \
      (__attribute__((address_space(3))) unsigned int*)(lp), 16, 0, 0)

__device__ __forceinline__ float bf2f(u16 u) {
  union { unsigned int i; float f; } v;
  v.i = ((unsigned int)u) << 16;
  return v.f;
}
__device__ __forceinline__ u16 f2bf(float f) {
  union { float f; unsigned int i; } v;
  v.f = f;
  unsigned int r = (v.i + 0x7fffu + ((v.i >> 16) & 1u)) >> 16;
  return (u16)r;
}
__device__ __forceinline__ float ldf(const void* p, size_t i, int isbf) {
  return isbf ? bf2f(((const u16*)p)[i]) : ((const float*)p)[i];
}
__device__ __forceinline__ float sigf(float x) { return 1.f / (1.f + __expf(-x)); }
__device__ __forceinline__ float tanhf_(float x) {
  float cx = fminf(fmaxf(x, -15.f), 15.f);
  float e = __expf(2.f * cx);
  return (e - 1.f) / (e + 1.f);
}
__device__ __forceinline__ float dot8_bf(const u16* w, const float* lp) {
  uint4 wv = *(const uint4*)w;
  union { unsigned int u; float f; } a0, a1;
  float s;
  a0.u = wv.x << 16; a1.u = wv.x & 0xffff0000u;
  s = lp[0] * a0.f + lp[1] * a1.f;
  a0.u = wv.y << 16; a1.u = wv.y & 0xffff0000u;
  s += lp[2] * a0.f + lp[3] * a1.f;
  a0.u = wv.z << 16; a1.u = wv.z & 0xffff0000u;
  s += lp[4] * a0.f + lp[5] * a1.f;
  a0.u = wv.w << 16; a1.u = wv.w & 0xffff0000u;
  s += lp[6] * a0.f + lp[7] * a1.f;
  return s;
}

// g' -> g permutation (shared by Wk/Wr repack and bias/wl)
__device__ __forceinline__ int gperm(int gp) {
  if (gp < 16) return gp;
  int r = gp - 16;
  int q = r & 3, h = r >> 2;
  return 16 + q * 384 + h;
}

// ------------------------- dtype detection (safety) ------------------------
__global__ void k_detect(const unsigned int* __restrict__ emb_raw,
                         int* __restrict__ flag) {
  if (blockIdx.x == 0 && threadIdx.x == 0) {
    int cnt = 0;
    for (int i = 64; i < 128; ++i) {
      unsigned int u = emb_raw[i];
      unsigned int lo = u & 0xffffu;
      unsigned int ex = (lo >> 7) & 0xffu;
      if (lo != 0 && ex >= 100 && ex <= 126) ++cnt;
    }
    *flag = (cnt >= 32) ? 1 : 0;
  }
}

// ------------------------- canonicalization --------------------------------
__global__ void k_cvt_emb(const void* __restrict__ src, u16* __restrict__ dst,
                          const int* __restrict__ flagp) {
  int isbf = *flagp;
  int n = 10001 * 128;
  int i = blockIdx.x * blockDim.x + threadIdx.x;
  int stride = gridDim.x * blockDim.x;
  for (; i < n; i += stride)
    dst[i] = isbf ? ((const u16*)src)[i] : f2bf(((const float*)src)[i]);
}

// wkp rows stored in g'-order (tile-local gate quads -> contiguous epilogue)
__global__ void k_repack_wk(const void* __restrict__ wk, u16* __restrict__ wkp,
                            const int* __restrict__ flagp) {
  int isbf = *flagp;
  size_t i = (size_t)blockIdx.x * blockDim.x + threadIdx.x;
  size_t total = (size_t)1664 * 8192;
  size_t stride = (size_t)gridDim.x * blockDim.x;
  for (; i < total; i += stride) {
    size_t gp = i >> 13, k = i & 8191;
    u16 v = (u16)0;
    if (gp < 1552) {
      int g = gperm((int)gp);
      v = f2bf(ldf(wk, (size_t)g * 8193 + k, isbf));
    }
    wkp[i] = v;
  }
}

// wrP2[g'][k] bf16 (permuted g'); biasC/wlC also in g'-order
__global__ void k_prep_wr2(const void* __restrict__ wr, const void* __restrict__ wk,
                           const void* __restrict__ bk, const void* __restrict__ br,
                           u16* __restrict__ wrP2, float* __restrict__ biasC,
                           float* __restrict__ wlC, const int* __restrict__ flagp) {
  int isbf = *flagp;
  int i0 = blockIdx.x * blockDim.x + threadIdx.x;
  int stride = gridDim.x * blockDim.x;
  for (int j = i0; j < 1552 * 384; j += stride) {
    int gp = j / 384, k = j - gp * 384;
    int g = gperm(gp);
    wrP2[j] = f2bf(ldf(wr, (size_t)g * 385 + k, isbf));
  }
  for (int gp = i0; gp < 1552; gp += stride) {
    int g = gperm(gp);
    biasC[gp] = ldf(bk, g, isbf) + ldf(br, g, isbf);
    wlC[gp] = ldf(wk, (size_t)g * 8193 + 8192, isbf) + ldf(wr, g * 385 + 384, isbf);
  }
}

__global__ void k_repack_wc(const void* __restrict__ wc, u16* __restrict__ wcp,
                            const int* __restrict__ flagp) {
  int isbf = *flagp;
  int i0 = blockIdx.x * blockDim.x + threadIdx.x;
  int stride = gridDim.x * blockDim.x;
  for (int j = i0; j < 384 * 3840; j += stride) {
    int o = j / 3840;
    int r = j - o * 3840;
    int k = r / 384;
    int h = r - k * 384;
    wcp[j] = f2bf(ldf(wc, (o * 384 + h) * 10 + k, isbf));  // [o][h][k]->[o][k][h]
  }
}

// canonical fp32: [vt 12800][Ws 24576][bs 64][Wrs 24576][brs 384][bc 384]
//                 [Wo 49152][bo 128]  (total 112064 floats)
__global__ void k_cvt_smalls(const void* vt, const void* Ws, const void* bs,
                             const void* Wrs, const void* brs, const void* bc,
                             const void* Wo, const void* bo,
                             float* __restrict__ dst, const int* __restrict__ flagp) {
  int isbf = *flagp;
  int i = blockIdx.x * blockDim.x + threadIdx.x;
  int stride = gridDim.x * blockDim.x;
  for (; i < 112064; i += stride) {
    float v;
    if (i < 12800) v = ldf(vt, i, isbf);
    else if (i < 37376) v = ldf(Ws, i - 12800, isbf);
    else if (i < 37440) v = ldf(bs, i - 37376, isbf);
    else if (i < 62016) v = ldf(Wrs, i - 37440, isbf);
    else if (i < 62400) v = ldf(brs, i - 62016, isbf);
    else if (i < 62784) v = ldf(bc, i - 62400, isbf);
    else if (i < 111936) v = ldf(Wo, i - 62784, isbf);
    else v = ldf(bo, i - 111936, isbf);
    dst[i] = v;
  }
}

__global__ void k_zero(float* __restrict__ p, int n) {
  int i = blockIdx.x * blockDim.x + threadIdx.x;
  int stride = gridDim.x * blockDim.x;
  for (; i < n; i += stride) p[i] = 0.f;
}

// ------------------------- PH1: gathered GEMM ------------------------------
// grid (100 m-tiles, 13 g'-tiles), m FAST (Wk panel L2-hot). Tile 128x128,
// BK=64 bf16. m' = t*256+b (t = m0>>8 const per tile). Wk/bias/wl already in
// g'-order -> epilogue stores are g'-contiguous (32B sector-aligned).
__global__ __launch_bounds__(256) void k_gemm_xk(
    const int* __restrict__ node_ids, const u16* __restrict__ embB,
    const u16* __restrict__ wkp, const float* __restrict__ vtF,
    const float* __restrict__ biasC, const float* __restrict__ wlC,
    u16* __restrict__ xkb) {
  __shared__ alignas(16) u16 As[128 * 64];
  __shared__ alignas(16) u16 Bs[128 * 64];
  int tid = threadIdx.x;
  int m0 = blockIdx.x * 128;
  int g0 = blockIdx.y * 128;
  int tq = m0 >> 8, b0t = m0 & 255;  // t const per tile; b-range [b0t, b0t+128)
  int lane = tid & 63, w = tid >> 6;
  int wy = w >> 1, wx = w & 1;
  f32x4 acc[4][4];
#pragma unroll
  for (int i = 0; i < 4; ++i)
#pragma unroll
    for (int j = 0; j < 4; ++j) acc[i][j] = (f32x4){0.f, 0.f, 0.f, 0.f};

  int l15 = lane & 15, lq = lane >> 4;
  int lr = lane >> 3, lc = lane & 7;  // row-in-chunk, 16B-chunk slot
  int swc = (lc ^ lr) * 8;            // swizzled global chunk offset (u16)
  int cRd = (lq ^ (l15 & 7)) * 8;     // swizzled read chunk, ks=0 (u16)

  for (int kt = 0; kt < 128; ++kt) {
    __syncthreads();
    // ---- stage A (gathered embed rows), swizzled global chunk
#pragma unroll
    for (int c = 0; c < 4; ++c) {
      int chunk = w * 4 + c;
      int r = chunk * 8 + lr;
      int id = node_ids[((size_t)(b0t + r) * 50 + tq) * 64 + (kt >> 1)];
      const u16* gp = embB + (size_t)id * 128 + (kt & 1) * 64 + swc;
      u16* lp = As + chunk * 512 + lane * 8;
      GLL(gp, lp);
    }
    // ---- stage B (Wk tile, g'-ordered rows), swizzled global chunk
#pragma unroll
    for (int c = 0; c < 4; ++c) {
      int chunk = w * 4 + c;
      int r = chunk * 8 + lr;
      const u16* gp = wkp + (size_t)(g0 + r) * 8192 + (size_t)kt * 64 + swc;
      u16* lp = Bs + chunk * 512 + lane * 8;
      GLL(gp, lp);
    }
    __syncthreads();
    const u16* Ab = As + (wy * 64 + l15) * 64;
    const u16* Bb = Bs + (wx * 64 + l15) * 64;
#pragma unroll
    for (int ks = 0; ks < 2; ++ks) {
      int co = cRd ^ (ks * 32);
      bf16x8 av[4], bv[4];
#pragma unroll
      for (int i = 0; i < 4; ++i) av[i] = *(const bf16x8*)(Ab + i * 1024 + co);
#pragma unroll
      for (int j = 0; j < 4; ++j) bv[j] = *(const bf16x8*)(Bb + j * 1024 + co);
#pragma unroll
      for (int i = 0; i < 4; ++i)
#pragma unroll
        for (int j = 0; j < 4; ++j)
          acc[i][j] =
              __builtin_amdgcn_mfma_f32_16x16x32_bf16(av[i], bv[j], acc[i][j], 0, 0, 0);
    }
  }
  float vt[4][4];
#pragma unroll
  for (int i = 0; i < 4; ++i)
#pragma unroll
    for (int p = 0; p < 4; ++p)
      vt[i][p] = vtF[(size_t)(b0t + wy * 64 + i * 16 + lq * 4 + p) * 50 + tq];
#pragma unroll
  for (int j = 0; j < 4; ++j) {
    int gcol = g0 + wx * 64 + j * 16 + l15;  // g' index, lane-contiguous
    if (gcol < 1552) {
      float bC = biasC[gcol], wC = wlC[gcol];
#pragma unroll
      for (int i = 0; i < 4; ++i)
#pragma unroll
        for (int p = 0; p < 4; ++p) {
          int row = wy * 64 + i * 16 + lq * 4 + p;
          xkb[(size_t)(m0 + row) * 1552 + gcol] =
              f2bf(acc[i][j][p] + bC + vt[i][p] * wC);
        }
    }
  }
}

// ------------------------- PH2: per-step g-split kernel --------------------
// grid (12 g-slices, 16 b-groups), 512 thr = 8 waves. Launch boundary = sync.
// Wave wv -> 16 permuted g'-rows; lane's D-frag = 4 gate pre-acts of
// (b=b0+l15, h=gs*32+wv*4+lq). fm/im tile 0 computed redundantly per block.
// c-state global f32 (same lane each launch); h double-buffered global bf16.
__global__ __launch_bounds__(512) void k_step2(
    const u16* __restrict__ xkb,   // [50][256][1552] bf16, permuted g'
    const u16* __restrict__ wrP2,  // [1552][384] bf16, permuted g'
    float* __restrict__ hbuf,      // [50][256][384] f32
    float* __restrict__ dbuf,      // [50][256] f32
    const u16* __restrict__ hin,   // [256][384] bf16 (h_{t-1})
    u16* __restrict__ hout,        // [256][384] bf16 (h_t)
    float* __restrict__ cst,       // [256][384] f32 (c state)
    int t) {
  __shared__ alignas(16) u16 hS[16 * 400];
  __shared__ alignas(16) float fmTile[16 * 17];
  __shared__ float fmS[16][8], imS[16][8];
  int tid = threadIdx.x;
  int gs = blockIdx.x, b0 = blockIdx.y * 16;
  int wv = tid >> 6, lane = tid & 63, l15 = lane & 15, lq = lane >> 4;

  int hmy = gs * 32 + wv * 4 + lq;  // this lane's h cell
  int bmy = b0 + l15;               // this lane's batch row

  // ---- early global loads (ILP): xk gate quad, softmax row, c state
  uint2 xkg = *(const uint2*)(xkb + ((size_t)t * 256 + bmy) * 1552 + 16 +
                              gs * 128 + wv * 16 + lq * 4);
  uint4 xksm = (uint4){0u, 0u, 0u, 0u};
  if (tid < 32)
    xksm = *(const uint4*)(xkb + ((size_t)t * 256 + b0 + (tid & 15)) * 1552 +
                           ((tid < 16) ? 0 : 8));
  float cv = cst[(size_t)bmy * 384 + hmy];

  // ---- stage h_{t-1} -> LDS (stride 400 u16)
  {
    const u16* hsrc = hin + (size_t)b0 * 384;
    for (int idx = tid; idx < 768; idx += 512) {
      int r = idx / 48, c = idx - r * 48;
      *(uint4*)(hS + r * 400 + c * 8) = *(const uint4*)(hsrc + r * 384 + c * 8);
    }
  }
  __syncthreads();

  // ---- B-frags (h_{t-1})
  bf16x8 hb[12];
#pragma unroll
  for (int ks = 0; ks < 12; ++ks)
    hb[ks] = *(const bf16x8*)(hS + l15 * 400 + ks * 32 + lq * 8);

  // ---- MFMA: gate tile (all waves) + fm/im tile 0 (wave 0)
  int gRow = 16 + gs * 128 + wv * 16 + l15;
  const u16* arow = wrP2 + (size_t)gRow * 384 + lq * 8;
  const u16* arow0 = wrP2 + (size_t)l15 * 384 + lq * 8;
  f32x4 accg = (f32x4){0.f, 0.f, 0.f, 0.f};
  f32x4 accf = (f32x4){0.f, 0.f, 0.f, 0.f};
#pragma unroll
  for (int ks = 0; ks < 12; ++ks) {
    bf16x8 ag = *(const bf16x8*)(arow + ks * 32);
    accg = __builtin_amdgcn_mfma_f32_16x16x32_bf16(ag, hb[ks], accg, 0, 0, 0);
    if (wv == 0) {
      bf16x8 a0 = *(const bf16x8*)(arow0 + ks * 32);
      accf = __builtin_amdgcn_mfma_f32_16x16x32_bf16(a0, hb[ks], accf, 0, 0, 0);
    }
  }
  if (wv == 0) {
#pragma unroll
    for (int p = 0; p < 4; ++p) fmTile[(lq * 4 + p) * 17 + l15] = accf[p];
  }
  __syncthreads();

  // ---- fm/im softmax (fm: tid<16, im: tid 16..31)
  if (tid < 32) {
    int r = tid & 15;
    const u16* xs = (const u16*)&xksm;
    float z[8], m = -1e30f;
#pragma unroll
    for (int j = 0; j < 8; ++j) {
      int jj = (tid < 16) ? j : (8 + j);
      z[j] = fmTile[jj * 17 + r] + bf2f(xs[j]);
      m = fmaxf(m, z[j]);
    }
    float s = 0.f;
#pragma unroll
    for (int j = 0; j < 8; ++j) { z[j] = __expf(z[j] - m); s += z[j]; }
    float inv = 1.f / s;
    if (tid < 16) {
      float run = 0.f, fsum = 0.f;
#pragma unroll
      for (int j = 0; j < 8; ++j) { run += z[j] * inv; fmS[r][j] = run; fsum += run; }
      if (gs == 0) dbuf[(size_t)t * 256 + b0 + r] = 1.f - fsum * 0.125f;
    } else {
      float run = 0.f;
#pragma unroll
      for (int j = 7; j >= 0; --j) { run += z[j] * inv; imS[r][j] = run; }
    }
  }
  __syncthreads();

  // ---- gates, fully in-register (one (b,h) cell per lane)
  {
    int lmy = hmy / 48;
    const u16* xg = (const u16*)&xkg;
    float x0 = accg[0] + bf2f(xg[0]);
    float x1 = accg[1] + bf2f(xg[1]);
    float x2 = accg[2] + bf2f(xg[2]);
    float x3 = accg[3] + bf2f(xg[3]);
    float fg = sigf(x0), ig = sigf(x1), og = sigf(x2), ci = tanhf_(x3);
    float fm = fmS[l15][lmy], im = imS[l15][lmy];
    float ov = fm * im;
    float cn = ov * (fg * cv + ig * ci) + (fm - ov) * cv + (im - ov) * ci;
    float hn = og * tanhf_(cn);
    cst[(size_t)bmy * 384 + hmy] = cn;
    hbuf[((size_t)t * 256 + bmy) * 384 + hmy] = hn;
    hout[(size_t)bmy * 384 + hmy] = f2bf(hn);
  }
}

// ------------------------- PH3: final (theme/conv/out) ---------------------
__global__ __launch_bounds__(384) void k_final(
    const float* __restrict__ hbuf, const float* __restrict__ dbuf,
    const unsigned char* __restrict__ am, const float* __restrict__ smalls,
    const u16* __restrict__ wcp, float* __restrict__ out) {
  const float* WsF = smalls + 12800;
  const float* bsF = smalls + 37376;
  const float* WrsF = smalls + 37440;
  const float* brsF = smalls + 62016;
  const float* bcF = smalls + 62400;
  const float* WoF = smalls + 62784;
  const float* boF = smalls + 111936;
  __shared__ alignas(16) float lh2[10][384];
  __shared__ alignas(16) float ti[384];
  __shared__ alignas(16) float us[64];
  __shared__ alignas(16) float rnnS[384];
  __shared__ alignas(16) float hlastS[384];
  __shared__ float ldS[10];
  __shared__ int npad[50];
  __shared__ int lastS;
  int tid = threadIdx.x;
  int b = blockIdx.x;

  if (tid < 50) {
    const unsigned char* mr = am + ((size_t)b * 50 + tid) * 64;
    int all1 = 1;
    for (int q = 0; q < 64; ++q) all1 &= (mr[q] != 0);
    npad[tid] = all1 ? 0 : 1;
  }
  __syncthreads();
  if (tid == 0) {
    int c = 0;
    for (int v = 0; v < 50; ++v) c += npad[v];
    int lv = c - 1;
    int last = lv < 0 ? 0 : lv;
    lastS = last;
    float cum = 0.f, cv[10];
    for (int k = 0; k < 10; ++k) {
      int s = last - 9 + k;
      float dk = (s >= 0) ? dbuf[(size_t)s * 256 + b] : 0.f;
      cum += dk;
      cv[k] = cum;
    }
    float m = cv[0];
    for (int k = 1; k < 10; ++k) m = fmaxf(m, cv[k]);
    float ssum = 0.f, ee[10];
    for (int k = 0; k < 10; ++k) { ee[k] = __expf(cv[k] - m); ssum += ee[k]; }
    float inv = 1.f / ssum;
    for (int k = 0; k < 10; ++k) ldS[k] = ee[k] * inv;
  }
  __syncthreads();
  {  // local_h, theme input, h_last
    int h = tid;
    int last = lastS;
    float ssum = 0.f;
    for (int k = 0; k < 10; ++k) {
      int s = last - 9 + k;
      float hv = (s >= 0) ? hbuf[((size_t)s * 256 + b) * 384 + h] : 0.f;
      float v = hv * ldS[k];
      lh2[k][h] = v;
      ssum += v;
    }
    ti[h] = ssum * 0.1f;
    hlastS[h] = hbuf[((size_t)last * 256 + b) * 384 + h];
  }
  __syncthreads();
  if (tid < 64) {  // u = relu(ti @ Ws^T + bs)
    float a = bsF[tid];
    const float* wr = WsF + (size_t)tid * 384;
    for (int h = 0; h < 384; ++h) a += wr[h] * ti[h];
    us[tid] = fmaxf(a, 0.f);
  }
  __syncthreads();
  {  // theme = sigmoid(u @ Wrs^T + brs); conv; rnn = theme*conv + h_last
    int o = tid;
    float th = brsF[o];
    const float* wr = WrsF + (size_t)o * 64;
    for (int k = 0; k < 64; ++k) th += wr[k] * us[k];
    th = sigf(th);
    float cacc = bcF[o];
    for (int k = 0; k < 10; ++k) {
      const u16* wrow = wcp + ((size_t)o * 10 + k) * 384;
      const float* lrow = lh2[k];
      for (int h8 = 0; h8 < 48; ++h8) cacc += dot8_bf(wrow + h8 * 8, lrow + h8 * 8);
    }
    rnnS[o] = th * cacc + hlastS[o];
  }
  __syncthreads();
  if (tid < 128) {  // out = rnn @ Wo^T + bo, fp32
    float a = boF[tid];
    const float* wr = WoF + (size_t)tid * 384;
    for (int h = 0; h < 384; ++h) a += wr[h] * rnnS[h];
    out[(size_t)b * 128 + tid] = a;
  }
}

// ------------------------- launch ------------------------------------------
extern "C" void kernel_launch(void* const* d_in, const int* in_sizes, int n_in,
                              void* d_out, int out_size, void* d_ws, size_t ws_size,
                              hipStream_t stream) {
  const int* node_ids = (const int*)d_in[0];
  const void* vtR = d_in[3];
  const unsigned char* am = (const unsigned char*)d_in[5];
  const void* embR = d_in[6];
  const void* WkR = d_in[7];
  const void* bkR = d_in[8];
  const void* WrR = d_in[9];
  const void* brR = d_in[10];
  const void* WsR = d_in[11];
  const void* bsR = d_in[12];
  const void* WrsR = d_in[13];
  const void* brsR = d_in[14];
  const void* WcR = d_in[15];
  const void* bcR = d_in[16];
  const void* WoR = d_in[17];
  const void* boR = d_in[18];
  (void)in_sizes; (void)n_in; (void)out_size; (void)ws_size;

  char* ws = (char*)d_ws;
  size_t off = 0;
  auto alloc = [&](size_t bytes) {
    void* p = ws + off;
    off = (off + bytes + 255) & ~(size_t)255;
    return p;
  };
  int* flagp = (int*)alloc(4);
  u16* embB = (u16*)alloc((size_t)10001 * 128 * 2);      // 2.56MB
  u16* WkP = (u16*)alloc((size_t)1664 * 8192 * 2);       // 27.3MB g'-ordered
  u16* WrP2 = (u16*)alloc((size_t)1552 * 384 * 2);       // 1.19MB bf16 permuted
  float* biasC = (float*)alloc(1552 * 4);
  float* wlC = (float*)alloc(1552 * 4);
  float* smalls = (float*)alloc((size_t)112064 * 4);
  u16* XKb = (u16*)alloc((size_t)12800 * 1552 * 2);      // 39.7MB [t][b][g']
  u16* WcP = (u16*)alloc((size_t)384 * 3840 * 2);        // 2.9MB
  float* Hbuf = (float*)alloc((size_t)50 * 256 * 384 * 4);  // 19.7MB
  float* Dbuf = (float*)alloc((size_t)50 * 256 * 4);
  u16* Hx = (u16*)alloc((size_t)2 * 256 * 384 * 2);      // 393KB
  float* Cst = (float*)alloc((size_t)256 * 384 * 4);     // 393KB

  k_detect<<<dim3(1), dim3(64), 0, stream>>>((const unsigned int*)embR, flagp);
  k_cvt_emb<<<dim3(1024), dim3(256), 0, stream>>>(embR, embB, flagp);
  k_repack_wk<<<dim3(2048), dim3(256), 0, stream>>>(WkR, WkP, flagp);
  k_prep_wr2<<<dim3(512), dim3(256), 0, stream>>>(WrR, WkR, bkR, brR, WrP2, biasC,
                                                  wlC, flagp);
  k_repack_wc<<<dim3(512), dim3(256), 0, stream>>>(WcR, WcP, flagp);
  k_cvt_smalls<<<dim3(128), dim3(256), 0, stream>>>(vtR, WsR, bsR, WrsR, brsR,
                                                    bcR, WoR, boR, smalls, flagp);
  k_zero<<<dim3(96), dim3(256), 0, stream>>>((float*)Hx, 98304);
  k_zero<<<dim3(96), dim3(256), 0, stream>>>(Cst, 98304);

  k_gemm_xk<<<dim3(100, 13), dim3(256), 0, stream>>>(node_ids, embB, WkP, smalls,
                                                     biasC, wlC, XKb);

  for (int t = 0; t < 50; ++t) {
    const u16* hin = Hx + (size_t)(t & 1) * (256 * 384);
    u16* hout = Hx + (size_t)((t + 1) & 1) * (256 * 384);
    k_step2<<<dim3(12, 16), dim3(512), 0, stream>>>(XKb, WrP2, Hbuf, Dbuf, hin,
                                                    hout, Cst, t);
  }

  k_final<<<dim3(256), dim3(384), 0, stream>>>(Hbuf, Dbuf, am, smalls, WcP,
                                               (float*)d_out);
}

// Round 8
// 1127.919 us; speedup vs baseline: 2.6512x; 1.0226x over previous
//
#include <hip/hip_runtime.h>
#include <stdint.h>

// ---------------------------------------------------------------------------
// StageNet forward on MI355X — ROUND 19.
// R18: 1153us. WRITE-amp fix confirmed (173->45MB) but time ~flat: gemm is
// structure/issue-bound (623 TF, MfmaUtil 27.7%). Counters show two residual
// overheads: FETCH 223MB = 8x Wk (each g-panel fetched by all 8 XCD L2s,
// m-fast dispatch) and per-kt node_ids global loads (4/lane/kt) feeding GLL.
// This round (gemm only, 128^2 structure kept):
//  * idS: tile's node_ids staged ONCE to LDS as u16 (16KB) -> K-loop id is
//    a ds_read_u16, no global loads in the staging address path.
//  * panel-clustered XCD mapping (bijective): lin->(xcd=lin&7, slot=lin>>3),
//    jobs panel-major per XCD (xcd<4: 163 jobs, else 162; total 1300).
//    Each XCD touches <=3 panels -> Wk HBM fetch ~20 panel-loads, not 104.
// Predicted: gemm FETCH 223->60-80MB, dur 560->480-510; total ~1060-1090us.
// ---------------------------------------------------------------------------

typedef unsigned short u16;
typedef short bf16x8 __attribute__((ext_vector_type(8)));
typedef float f32x4 __attribute__((ext_vector_type(4)));

#define GLL(gp, lp)                                                            \
  __builtin_amdgcn_global_load_lds(                                            \
      (const __attribute__((address_space(1))) unsigned int*)(gp),             \
      (__attribute__((address_space(3))) unsigned int*)(lp), 16, 0, 0)

__device__ __forceinline__ float bf2f(u16 u) {
  union { unsigned int i; float f; } v;
  v.i = ((unsigned int)u) << 16;
  return v.f;
}
__device__ __forceinline__ u16 f2bf(float f) {
  union { float f; unsigned int i; } v;
  v.f = f;
  unsigned int r = (v.i + 0x7fffu + ((v.i >> 16) & 1u)) >> 16;
  return (u16)r;
}
__device__ __forceinline__ float ldf(const void* p, size_t i, int isbf) {
  return isbf ? bf2f(((const u16*)p)[i]) : ((const float*)p)[i];
}
__device__ __forceinline__ float sigf(float x) { return 1.f / (1.f + __expf(-x)); }
__device__ __forceinline__ float tanhf_(float x) {
  float cx = fminf(fmaxf(x, -15.f), 15.f);
  float e = __expf(2.f * cx);
  return (e - 1.f) / (e + 1.f);
}
__device__ __forceinline__ float dot8_bf(const u16* w, const float* lp) {
  uint4 wv = *(const uint4*)w;
  union { unsigned int u; float f; } a0, a1;
  float s;
  a0.u = wv.x << 16; a1.u = wv.x & 0xffff0000u;
  s = lp[0] * a0.f + lp[1] * a1.f;
  a0.u = wv.y << 16; a1.u = wv.y & 0xffff0000u;
  s += lp[2] * a0.f + lp[3] * a1.f;
  a0.u = wv.z << 16; a1.u = wv.z & 0xffff0000u;
  s += lp[4] * a0.f + lp[5] * a1.f;
  a0.u = wv.w << 16; a1.u = wv.w & 0xffff0000u;
  s += lp[6] * a0.f + lp[7] * a1.f;
  return s;
}

// g' -> g permutation (shared by Wk/Wr repack and bias/wl)
__device__ __forceinline__ int gperm(int gp) {
  if (gp < 16) return gp;
  int r = gp - 16;
  int q = r & 3, h = r >> 2;
  return 16 + q * 384 + h;
}

// ------------------------- dtype detection (safety) ------------------------
__global__ void k_detect(const unsigned int* __restrict__ emb_raw,
                         int* __restrict__ flag) {
  if (blockIdx.x == 0 && threadIdx.x == 0) {
    int cnt = 0;
    for (int i = 64; i < 128; ++i) {
      unsigned int u = emb_raw[i];
      unsigned int lo = u & 0xffffu;
      unsigned int ex = (lo >> 7) & 0xffu;
      if (lo != 0 && ex >= 100 && ex <= 126) ++cnt;
    }
    *flag = (cnt >= 32) ? 1 : 0;
  }
}

// ------------------------- canonicalization --------------------------------
__global__ void k_cvt_emb(const void* __restrict__ src, u16* __restrict__ dst,
                          const int* __restrict__ flagp) {
  int isbf = *flagp;
  int n = 10001 * 128;
  int i = blockIdx.x * blockDim.x + threadIdx.x;
  int stride = gridDim.x * blockDim.x;
  for (; i < n; i += stride)
    dst[i] = isbf ? ((const u16*)src)[i] : f2bf(((const float*)src)[i]);
}

// wkp rows stored in g'-order (tile-local gate quads -> contiguous epilogue)
__global__ void k_repack_wk(const void* __restrict__ wk, u16* __restrict__ wkp,
                            const int* __restrict__ flagp) {
  int isbf = *flagp;
  size_t i = (size_t)blockIdx.x * blockDim.x + threadIdx.x;
  size_t total = (size_t)1664 * 8192;
  size_t stride = (size_t)gridDim.x * blockDim.x;
  for (; i < total; i += stride) {
    size_t gp = i >> 13, k = i & 8191;
    u16 v = (u16)0;
    if (gp < 1552) {
      int g = gperm((int)gp);
      v = f2bf(ldf(wk, (size_t)g * 8193 + k, isbf));
    }
    wkp[i] = v;
  }
}

// wrP2[g'][k] bf16 (permuted g'); biasC/wlC also in g'-order
__global__ void k_prep_wr2(const void* __restrict__ wr, const void* __restrict__ wk,
                           const void* __restrict__ bk, const void* __restrict__ br,
                           u16* __restrict__ wrP2, float* __restrict__ biasC,
                           float* __restrict__ wlC, const int* __restrict__ flagp) {
  int isbf = *flagp;
  int i0 = blockIdx.x * blockDim.x + threadIdx.x;
  int stride = gridDim.x * blockDim.x;
  for (int j = i0; j < 1552 * 384; j += stride) {
    int gp = j / 384, k = j - gp * 384;
    int g = gperm(gp);
    wrP2[j] = f2bf(ldf(wr, (size_t)g * 385 + k, isbf));
  }
  for (int gp = i0; gp < 1552; gp += stride) {
    int g = gperm(gp);
    biasC[gp] = ldf(bk, g, isbf) + ldf(br, g, isbf);
    wlC[gp] = ldf(wk, (size_t)g * 8193 + 8192, isbf) + ldf(wr, g * 385 + 384, isbf);
  }
}

__global__ void k_repack_wc(const void* __restrict__ wc, u16* __restrict__ wcp,
                            const int* __restrict__ flagp) {
  int isbf = *flagp;
  int i0 = blockIdx.x * blockDim.x + threadIdx.x;
  int stride = gridDim.x * blockDim.x;
  for (int j = i0; j < 384 * 3840; j += stride) {
    int o = j / 3840;
    int r = j - o * 3840;
    int k = r / 384;
    int h = r - k * 384;
    wcp[j] = f2bf(ldf(wc, (o * 384 + h) * 10 + k, isbf));  // [o][h][k]->[o][k][h]
  }
}

// canonical fp32: [vt 12800][Ws 24576][bs 64][Wrs 24576][brs 384][bc 384]
//                 [Wo 49152][bo 128]  (total 112064 floats)
__global__ void k_cvt_smalls(const void* vt, const void* Ws, const void* bs,
                             const void* Wrs, const void* brs, const void* bc,
                             const void* Wo, const void* bo,
                             float* __restrict__ dst, const int* __restrict__ flagp) {
  int isbf = *flagp;
  int i = blockIdx.x * blockDim.x + threadIdx.x;
  int stride = gridDim.x * blockDim.x;
  for (; i < 112064; i += stride) {
    float v;
    if (i < 12800) v = ldf(vt, i, isbf);
    else if (i < 37376) v = ldf(Ws, i - 12800, isbf);
    else if (i < 37440) v = ldf(bs, i - 37376, isbf);
    else if (i < 62016) v = ldf(Wrs, i - 37440, isbf);
    else if (i < 62400) v = ldf(brs, i - 62016, isbf);
    else if (i < 62784) v = ldf(bc, i - 62400, isbf);
    else if (i < 111936) v = ldf(Wo, i - 62784, isbf);
    else v = ldf(bo, i - 111936, isbf);
    dst[i] = v;
  }
}

__global__ void k_zero(float* __restrict__ p, int n) {
  int i = blockIdx.x * blockDim.x + threadIdx.x;
  int stride = gridDim.x * blockDim.x;
  for (; i < n; i += stride) p[i] = 0.f;
}

// ------------------------- PH1: gathered GEMM ------------------------------
// Linear grid 1300, panel-clustered XCD mapping: xcd=lin&7, slot=lin>>3,
// job panel-major per XCD (xcd<4: 163 jobs, else 162) -> each XCD L2 touches
// <=3 Wk panels. Tile 128x128, BK=64 bf16. node_ids staged once to LDS (u16).
// Wk/bias/wl in g'-order; epilogue stores g'-contiguous.
__global__ __launch_bounds__(256) void k_gemm_xk(
    const int* __restrict__ node_ids, const u16* __restrict__ embB,
    const u16* __restrict__ wkp, const float* __restrict__ vtF,
    const float* __restrict__ biasC, const float* __restrict__ wlC,
    u16* __restrict__ xkb) {
  __shared__ alignas(16) u16 As[128 * 64];
  __shared__ alignas(16) u16 Bs[128 * 64];
  __shared__ alignas(16) u16 idS[128 * 64];  // tile's node ids (u16, <10001)
  int tid = threadIdx.x;
  // bijective panel-clustered mapping over 1300 jobs
  int lin = blockIdx.x;
  int xcd = lin & 7, slot = lin >> 3;
  int job = (xcd < 4) ? (xcd * 163 + slot) : (4 * 163 + (xcd - 4) * 162 + slot);
  int mb = job % 100, gb = job / 100;
  int m0 = mb * 128;
  int g0 = gb * 128;
  int tq = m0 >> 8, b0t = m0 & 255;  // t const per tile; b-range [b0t, b0t+128)
  int lane = tid & 63, w = tid >> 6;
  int wy = w >> 1, wx = w & 1;
  f32x4 acc[4][4];
#pragma unroll
  for (int i = 0; i < 4; ++i)
#pragma unroll
    for (int j = 0; j < 4; ++j) acc[i][j] = (f32x4){0.f, 0.f, 0.f, 0.f};

  // ---- stage node ids once (row-major int4 loads, u16 LDS store)
  {
    const int4* nb = (const int4*)(node_ids + ((size_t)b0t * 50 + tq) * 64);
    for (int i = tid; i < 2048; i += 256) {
      int row = i >> 4, c4 = i & 15;
      int4 v = nb[(size_t)row * 800 + c4];  // row stride 50*64/4 = 800 int4
      u16* d = idS + row * 64 + c4 * 4;
      d[0] = (u16)v.x; d[1] = (u16)v.y; d[2] = (u16)v.z; d[3] = (u16)v.w;
    }
  }

  int l15 = lane & 15, lq = lane >> 4;
  int lr = lane >> 3, lc = lane & 7;  // row-in-chunk, 16B-chunk slot
  int swc = (lc ^ lr) * 8;            // swizzled global chunk offset (u16)
  int cRd = (lq ^ (l15 & 7)) * 8;     // swizzled read chunk, ks=0 (u16)

  for (int kt = 0; kt < 128; ++kt) {
    __syncthreads();  // covers idS staging (kt=0) + As/Bs reuse (kt>0)
    // ---- stage A (gathered embed rows), swizzled global chunk
#pragma unroll
    for (int c = 0; c < 4; ++c) {
      int chunk = w * 4 + c;
      int r = chunk * 8 + lr;
      int id = (int)idS[r * 64 + (kt >> 1)];
      const u16* gp = embB + (size_t)id * 128 + (kt & 1) * 64 + swc;
      u16* lp = As + chunk * 512 + lane * 8;
      GLL(gp, lp);
    }
    // ---- stage B (Wk tile, g'-ordered rows), swizzled global chunk
#pragma unroll
    for (int c = 0; c < 4; ++c) {
      int chunk = w * 4 + c;
      int r = chunk * 8 + lr;
      const u16* gp = wkp + (size_t)(g0 + r) * 8192 + (size_t)kt * 64 + swc;
      u16* lp = Bs + chunk * 512 + lane * 8;
      GLL(gp, lp);
    }
    __syncthreads();
    const u16* Ab = As + (wy * 64 + l15) * 64;
    const u16* Bb = Bs + (wx * 64 + l15) * 64;
#pragma unroll
    for (int ks = 0; ks < 2; ++ks) {
      int co = cRd ^ (ks * 32);
      bf16x8 av[4], bv[4];
#pragma unroll
      for (int i = 0; i < 4; ++i) av[i] = *(const bf16x8*)(Ab + i * 1024 + co);
#pragma unroll
      for (int j = 0; j < 4; ++j) bv[j] = *(const bf16x8*)(Bb + j * 1024 + co);
#pragma unroll
      for (int i = 0; i < 4; ++i)
#pragma unroll
        for (int j = 0; j < 4; ++j)
          acc[i][j] =
              __builtin_amdgcn_mfma_f32_16x16x32_bf16(av[i], bv[j], acc[i][j], 0, 0, 0);
    }
  }
  float vt[4][4];
#pragma unroll
  for (int i = 0; i < 4; ++i)
#pragma unroll
    for (int p = 0; p < 4; ++p)
      vt[i][p] = vtF[(size_t)(b0t + wy * 64 + i * 16 + lq * 4 + p) * 50 + tq];
#pragma unroll
  for (int j = 0; j < 4; ++j) {
    int gcol = g0 + wx * 64 + j * 16 + l15;  // g' index, lane-contiguous
    if (gcol < 1552) {
      float bC = biasC[gcol], wC = wlC[gcol];
#pragma unroll
      for (int i = 0; i < 4; ++i)
#pragma unroll
        for (int p = 0; p < 4; ++p) {
          int row = wy * 64 + i * 16 + lq * 4 + p;
          xkb[(size_t)(m0 + row) * 1552 + gcol] =
              f2bf(acc[i][j][p] + bC + vt[i][p] * wC);
        }
    }
  }
}

// ------------------------- PH2: per-step g-split kernel --------------------
// grid (12 g-slices, 16 b-groups), 512 thr = 8 waves. Launch boundary = sync.
// Wave wv -> 16 permuted g'-rows; lane's D-frag = 4 gate pre-acts of
// (b=b0+l15, h=gs*32+wv*4+lq). fm/im tile 0 computed redundantly per block.
// c-state global f32 (same lane each launch); h double-buffered global bf16.
__global__ __launch_bounds__(512) void k_step2(
    const u16* __restrict__ xkb,   // [50][256][1552] bf16, permuted g'
    const u16* __restrict__ wrP2,  // [1552][384] bf16, permuted g'
    float* __restrict__ hbuf,      // [50][256][384] f32
    float* __restrict__ dbuf,      // [50][256] f32
    const u16* __restrict__ hin,   // [256][384] bf16 (h_{t-1})
    u16* __restrict__ hout,        // [256][384] bf16 (h_t)
    float* __restrict__ cst,       // [256][384] f32 (c state)
    int t) {
  __shared__ alignas(16) u16 hS[16 * 400];
  __shared__ alignas(16) float fmTile[16 * 17];
  __shared__ float fmS[16][8], imS[16][8];
  int tid = threadIdx.x;
  int gs = blockIdx.x, b0 = blockIdx.y * 16;
  int wv = tid >> 6, lane = tid & 63, l15 = lane & 15, lq = lane >> 4;

  int hmy = gs * 32 + wv * 4 + lq;  // this lane's h cell
  int bmy = b0 + l15;               // this lane's batch row

  // ---- early global loads (ILP): xk gate quad, softmax row, c state
  uint2 xkg = *(const uint2*)(xkb + ((size_t)t * 256 + bmy) * 1552 + 16 +
                              gs * 128 + wv * 16 + lq * 4);
  uint4 xksm = (uint4){0u, 0u, 0u, 0u};
  if (tid < 32)
    xksm = *(const uint4*)(xkb + ((size_t)t * 256 + b0 + (tid & 15)) * 1552 +
                           ((tid < 16) ? 0 : 8));
  float cv = cst[(size_t)bmy * 384 + hmy];

  // ---- stage h_{t-1} -> LDS (stride 400 u16)
  {
    const u16* hsrc = hin + (size_t)b0 * 384;
    for (int idx = tid; idx < 768; idx += 512) {
      int r = idx / 48, c = idx - r * 48;
      *(uint4*)(hS + r * 400 + c * 8) = *(const uint4*)(hsrc + r * 384 + c * 8);
    }
  }
  __syncthreads();

  // ---- B-frags (h_{t-1})
  bf16x8 hb[12];
#pragma unroll
  for (int ks = 0; ks < 12; ++ks)
    hb[ks] = *(const bf16x8*)(hS + l15 * 400 + ks * 32 + lq * 8);

  // ---- MFMA: gate tile (all waves) + fm/im tile 0 (wave 0)
  int gRow = 16 + gs * 128 + wv * 16 + l15;
  const u16* arow = wrP2 + (size_t)gRow * 384 + lq * 8;
  const u16* arow0 = wrP2 + (size_t)l15 * 384 + lq * 8;
  f32x4 accg = (f32x4){0.f, 0.f, 0.f, 0.f};
  f32x4 accf = (f32x4){0.f, 0.f, 0.f, 0.f};
#pragma unroll
  for (int ks = 0; ks < 12; ++ks) {
    bf16x8 ag = *(const bf16x8*)(arow + ks * 32);
    accg = __builtin_amdgcn_mfma_f32_16x16x32_bf16(ag, hb[ks], accg, 0, 0, 0);
    if (wv == 0) {
      bf16x8 a0 = *(const bf16x8*)(arow0 + ks * 32);
      accf = __builtin_amdgcn_mfma_f32_16x16x32_bf16(a0, hb[ks], accf, 0, 0, 0);
    }
  }
  if (wv == 0) {
#pragma unroll
    for (int p = 0; p < 4; ++p) fmTile[(lq * 4 + p) * 17 + l15] = accf[p];
  }
  __syncthreads();

  // ---- fm/im softmax (fm: tid<16, im: tid 16..31)
  if (tid < 32) {
    int r = tid & 15;
    const u16* xs = (const u16*)&xksm;
    float z[8], m = -1e30f;
#pragma unroll
    for (int j = 0; j < 8; ++j) {
      int jj = (tid < 16) ? j : (8 + j);
      z[j] = fmTile[jj * 17 + r] + bf2f(xs[j]);
      m = fmaxf(m, z[j]);
    }
    float s = 0.f;
#pragma unroll
    for (int j = 0; j < 8; ++j) { z[j] = __expf(z[j] - m); s += z[j]; }
    float inv = 1.f / s;
    if (tid < 16) {
      float run = 0.f, fsum = 0.f;
#pragma unroll
      for (int j = 0; j < 8; ++j) { run += z[j] * inv; fmS[r][j] = run; fsum += run; }
      if (gs == 0) dbuf[(size_t)t * 256 + b0 + r] = 1.f - fsum * 0.125f;
    } else {
      float run = 0.f;
#pragma unroll
      for (int j = 7; j >= 0; --j) { run += z[j] * inv; imS[r][j] = run; }
    }
  }
  __syncthreads();

  // ---- gates, fully in-register (one (b,h) cell per lane)
  {
    int lmy = hmy / 48;
    const u16* xg = (const u16*)&xkg;
    float x0 = accg[0] + bf2f(xg[0]);
    float x1 = accg[1] + bf2f(xg[1]);
    float x2 = accg[2] + bf2f(xg[2]);
    float x3 = accg[3] + bf2f(xg[3]);
    float fg = sigf(x0), ig = sigf(x1), og = sigf(x2), ci = tanhf_(x3);
    float fm = fmS[l15][lmy], im = imS[l15][lmy];
    float ov = fm * im;
    float cn = ov * (fg * cv + ig * ci) + (fm - ov) * cv + (im - ov) * ci;
    float hn = og * tanhf_(cn);
    cst[(size_t)bmy * 384 + hmy] = cn;
    hbuf[((size_t)t * 256 + bmy) * 384 + hmy] = hn;
    hout[(size_t)bmy * 384 + hmy] = f2bf(hn);
  }
}

// ------------------------- PH3: final (theme/conv/out) ---------------------
__global__ __launch_bounds__(384) void k_final(
    const float* __restrict__ hbuf, const float* __restrict__ dbuf,
    const unsigned char* __restrict__ am, const float* __restrict__ smalls,
    const u16* __restrict__ wcp, float* __restrict__ out) {
  const float* WsF = smalls + 12800;
  const float* bsF = smalls + 37376;
  const float* WrsF = smalls + 37440;
  const float* brsF = smalls + 62016;
  const float* bcF = smalls + 62400;
  const float* WoF = smalls + 62784;
  const float* boF = smalls + 111936;
  __shared__ alignas(16) float lh2[10][384];
  __shared__ alignas(16) float ti[384];
  __shared__ alignas(16) float us[64];
  __shared__ alignas(16) float rnnS[384];
  __shared__ alignas(16) float hlastS[384];
  __shared__ float ldS[10];
  __shared__ int npad[50];
  __shared__ int lastS;
  int tid = threadIdx.x;
  int b = blockIdx.x;

  if (tid < 50) {
    const unsigned char* mr = am + ((size_t)b * 50 + tid) * 64;
    int all1 = 1;
    for (int q = 0; q < 64; ++q) all1 &= (mr[q] != 0);
    npad[tid] = all1 ? 0 : 1;
  }
  __syncthreads();
  if (tid == 0) {
    int c = 0;
    for (int v = 0; v < 50; ++v) c += npad[v];
    int lv = c - 1;
    int last = lv < 0 ? 0 : lv;
    lastS = last;
    float cum = 0.f, cv[10];
    for (int k = 0; k < 10; ++k) {
      int s = last - 9 + k;
      float dk = (s >= 0) ? dbuf[(size_t)s * 256 + b] : 0.f;
      cum += dk;
      cv[k] = cum;
    }
    float m = cv[0];
    for (int k = 1; k < 10; ++k) m = fmaxf(m, cv[k]);
    float ssum = 0.f, ee[10];
    for (int k = 0; k < 10; ++k) { ee[k] = __expf(cv[k] - m); ssum += ee[k]; }
    float inv = 1.f / ssum;
    for (int k = 0; k < 10; ++k) ldS[k] = ee[k] * inv;
  }
  __syncthreads();
  {  // local_h, theme input, h_last
    int h = tid;
    int last = lastS;
    float ssum = 0.f;
    for (int k = 0; k < 10; ++k) {
      int s = last - 9 + k;
      float hv = (s >= 0) ? hbuf[((size_t)s * 256 + b) * 384 + h] : 0.f;
      float v = hv * ldS[k];
      lh2[k][h] = v;
      ssum += v;
    }
    ti[h] = ssum * 0.1f;
    hlastS[h] = hbuf[((size_t)last * 256 + b) * 384 + h];
  }
  __syncthreads();
  if (tid < 64) {  // u = relu(ti @ Ws^T + bs)
    float a = bsF[tid];
    const float* wr = WsF + (size_t)tid * 384;
    for (int h = 0; h < 384; ++h) a += wr[h] * ti[h];
    us[tid] = fmaxf(a, 0.f);
  }
  __syncthreads();
  {  // theme = sigmoid(u @ Wrs^T + brs); conv; rnn = theme*conv + h_last
    int o = tid;
    float th = brsF[o];
    const float* wr = WrsF + (size_t)o * 64;
    for (int k = 0; k < 64; ++k) th += wr[k] * us[k];
    th = sigf(th);
    float cacc = bcF[o];
    for (int k = 0; k < 10; ++k) {
      const u16* wrow = wcp + ((size_t)o * 10 + k) * 384;
      const float* lrow = lh2[k];
      for (int h8 = 0; h8 < 48; ++h8) cacc += dot8_bf(wrow + h8 * 8, lrow + h8 * 8);
    }
    rnnS[o] = th * cacc + hlastS[o];
  }
  __syncthreads();
  if (tid < 128) {  // out = rnn @ Wo^T + bo, fp32
    float a = boF[tid];
    const float* wr = WoF + (size_t)tid * 384;
    for (int h = 0; h < 384; ++h) a += wr[h] * rnnS[h];
    out[(size_t)b * 128 + tid] = a;
  }
}

// ------------------------- launch ------------------------------------------
extern "C" void kernel_launch(void* const* d_in, const int* in_sizes, int n_in,
                              void* d_out, int out_size, void* d_ws, size_t ws_size,
                              hipStream_t stream) {
  const int* node_ids = (const int*)d_in[0];
  const void* vtR = d_in[3];
  const unsigned char* am = (const unsigned char*)d_in[5];
  const void* embR = d_in[6];
  const void* WkR = d_in[7];
  const void* bkR = d_in[8];
  const void* WrR = d_in[9];
  const void* brR = d_in[10];
  const void* WsR = d_in[11];
  const void* bsR = d_in[12];
  const void* WrsR = d_in[13];
  const void* brsR = d_in[14];
  const void* WcR = d_in[15];
  const void* bcR = d_in[16];
  const void* WoR = d_in[17];
  const void* boR = d_in[18];
  (void)in_sizes; (void)n_in; (void)out_size; (void)ws_size;

  char* ws = (char*)d_ws;
  size_t off = 0;
  auto alloc = [&](size_t bytes) {
    void* p = ws + off;
    off = (off + bytes + 255) & ~(size_t)255;
    return p;
  };
  int* flagp = (int*)alloc(4);
  u16* embB = (u16*)alloc((size_t)10001 * 128 * 2);      // 2.56MB
  u16* WkP = (u16*)alloc((size_t)1664 * 8192 * 2);       // 27.3MB g'-ordered
  u16* WrP2 = (u16*)alloc((size_t)1552 * 384 * 2);       // 1.19MB bf16 permuted
  float* biasC = (float*)alloc(1552 * 4);
  float* wlC = (float*)alloc(1552 * 4);
  float* smalls = (float*)alloc((size_t)112064 * 4);
  u16* XKb = (u16*)alloc((size_t)12800 * 1552 * 2);      // 39.7MB [t][b][g']
  u16* WcP = (u16*)alloc((size_t)384 * 3840 * 2);        // 2.9MB
  float* Hbuf = (float*)alloc((size_t)50 * 256 * 384 * 4);  // 19.7MB
  float* Dbuf = (float*)alloc((size_t)50 * 256 * 4);
  u16* Hx = (u16*)alloc((size_t)2 * 256 * 384 * 2);      // 393KB
  float* Cst = (float*)alloc((size_t)256 * 384 * 4);     // 393KB

  k_detect<<<dim3(1), dim3(64), 0, stream>>>((const unsigned int*)embR, flagp);
  k_cvt_emb<<<dim3(1024), dim3(256), 0, stream>>>(embR, embB, flagp);
  k_repack_wk<<<dim3(2048), dim3(256), 0, stream>>>(WkR, WkP, flagp);
  k_prep_wr2<<<dim3(512), dim3(256), 0, stream>>>(WrR, WkR, bkR, brR, WrP2, biasC,
                                                  wlC, flagp);
  k_repack_wc<<<dim3(512), dim3(256), 0, stream>>>(WcR, WcP, flagp);
  k_cvt_smalls<<<dim3(128), dim3(256), 0, stream>>>(vtR, WsR, bsR, WrsR, brsR,
                                                    bcR, WoR, boR, smalls, flagp);
  k_zero<<<dim3(96), dim3(256), 0, stream>>>((float*)Hx, 98304);
  k_zero<<<dim3(96), dim3(256), 0, stream>>>(Cst, 98304);

  k_gemm_xk<<<dim3(1300), dim3(256), 0, stream>>>(node_ids, embB, WkP, smalls,
                                                  biasC, wlC, XKb);

  for (int t = 0; t < 50; ++t) {
    const u16* hin = Hx + (size_t)(t & 1) * (256 * 384);
    u16* hout = Hx + (size_t)((t + 1) & 1) * (256 * 384);
    k_step2<<<dim3(12, 16), dim3(512), 0, stream>>>(XKb, WrP2, Hbuf, Dbuf, hin,
                                                    hout, Cst, t);
  }

  k_final<<<dim3(256), dim3(384), 0, stream>>>(Hbuf, Dbuf, am, smalls, WcP,
                                               (float*)d_out);
}

// Round 9
// 993.235 us; speedup vs baseline: 3.0107x; 1.1356x over previous
//
#include <hip/hip_runtime.h>
#include <stdint.h>

// ---------------------------------------------------------------------------
// StageNet forward on MI355X — ROUND 20.
// R19: 1128us = gemm 489 + step-chain ~536 (launch-bound) + final/prep ~100.
// R14's barrier disaster re-diagnosed: ACQUIRE/RELEASE -> buffer_wbl2/inv
// per block-step (L2 flush). The cheap coherent path: RELAXED agent-scope
// atomics (LLC-point flagged ops, NO cache maintenance) + vmcnt(0) ordering.
// This round:
//  * k_scan5: persistent 192 blocks (1/CU via 128KB LDS -> co-residency
//    guaranteed), Wr slice LDS-resident (loaded once). Per step: h staged
//    via relaxed-agent u32 atomic loads; MFMA + in-register gates (k_step2
//    math verbatim); h bf16-pairs stored via relaxed-agent atomics;
//    vmcnt(0) -> per-b-group 12-block monotonic counter barrier (relaxed
//    only). 49 launch boundaries eliminated.
//  * gemm: idS stride 64->66 u16 (kills the 16M bank conflicts R19 added).
// Predicted: scan 90-160us, gemm ~460, total ~700-780us.
// Fallback if absmax/hang: revert scan to R19 relaunch chain.
// ---------------------------------------------------------------------------

typedef unsigned short u16;
typedef short bf16x8 __attribute__((ext_vector_type(8)));
typedef float f32x4 __attribute__((ext_vector_type(4)));

#define GLL(gp, lp)                                                            \
  __builtin_amdgcn_global_load_lds(                                            \
      (const __attribute__((address_space(1))) unsigned int*)(gp),             \
      (__attribute__((address_space(3))) unsigned int*)(lp), 16, 0, 0)

__device__ __forceinline__ float bf2f(u16 u) {
  union { unsigned int i; float f; } v;
  v.i = ((unsigned int)u) << 16;
  return v.f;
}
__device__ __forceinline__ u16 f2bf(float f) {
  union { float f; unsigned int i; } v;
  v.f = f;
  unsigned int r = (v.i + 0x7fffu + ((v.i >> 16) & 1u)) >> 16;
  return (u16)r;
}
__device__ __forceinline__ float ldf(const void* p, size_t i, int isbf) {
  return isbf ? bf2f(((const u16*)p)[i]) : ((const float*)p)[i];
}
__device__ __forceinline__ float sigf(float x) { return 1.f / (1.f + __expf(-x)); }
__device__ __forceinline__ float tanhf_(float x) {
  float cx = fminf(fmaxf(x, -15.f), 15.f);
  float e = __expf(2.f * cx);
  return (e - 1.f) / (e + 1.f);
}
__device__ __forceinline__ float dot8_bf(const u16* w, const float* lp) {
  uint4 wv = *(const uint4*)w;
  union { unsigned int u; float f; } a0, a1;
  float s;
  a0.u = wv.x << 16; a1.u = wv.x & 0xffff0000u;
  s = lp[0] * a0.f + lp[1] * a1.f;
  a0.u = wv.y << 16; a1.u = wv.y & 0xffff0000u;
  s += lp[2] * a0.f + lp[3] * a1.f;
  a0.u = wv.z << 16; a1.u = wv.z & 0xffff0000u;
  s += lp[4] * a0.f + lp[5] * a1.f;
  a0.u = wv.w << 16; a1.u = wv.w & 0xffff0000u;
  s += lp[6] * a0.f + lp[7] * a1.f;
  return s;
}

// g' -> g permutation (shared by Wk/Wr repack and bias/wl)
__device__ __forceinline__ int gperm(int gp) {
  if (gp < 16) return gp;
  int r = gp - 16;
  int q = r & 3, h = r >> 2;
  return 16 + q * 384 + h;
}

// ------------------------- dtype detection (safety) ------------------------
__global__ void k_detect(const unsigned int* __restrict__ emb_raw,
                         int* __restrict__ flag) {
  if (blockIdx.x == 0 && threadIdx.x == 0) {
    int cnt = 0;
    for (int i = 64; i < 128; ++i) {
      unsigned int u = emb_raw[i];
      unsigned int lo = u & 0xffffu;
      unsigned int ex = (lo >> 7) & 0xffu;
      if (lo != 0 && ex >= 100 && ex <= 126) ++cnt;
    }
    *flag = (cnt >= 32) ? 1 : 0;
  }
}

// ------------------------- canonicalization --------------------------------
__global__ void k_cvt_emb(const void* __restrict__ src, u16* __restrict__ dst,
                          const int* __restrict__ flagp) {
  int isbf = *flagp;
  int n = 10001 * 128;
  int i = blockIdx.x * blockDim.x + threadIdx.x;
  int stride = gridDim.x * blockDim.x;
  for (; i < n; i += stride)
    dst[i] = isbf ? ((const u16*)src)[i] : f2bf(((const float*)src)[i]);
}

// wkp rows stored in g'-order (tile-local gate quads -> contiguous epilogue)
__global__ void k_repack_wk(const void* __restrict__ wk, u16* __restrict__ wkp,
                            const int* __restrict__ flagp) {
  int isbf = *flagp;
  size_t i = (size_t)blockIdx.x * blockDim.x + threadIdx.x;
  size_t total = (size_t)1664 * 8192;
  size_t stride = (size_t)gridDim.x * blockDim.x;
  for (; i < total; i += stride) {
    size_t gp = i >> 13, k = i & 8191;
    u16 v = (u16)0;
    if (gp < 1552) {
      int g = gperm((int)gp);
      v = f2bf(ldf(wk, (size_t)g * 8193 + k, isbf));
    }
    wkp[i] = v;
  }
}

// wrP2[g'][k] bf16 (permuted g'); biasC/wlC also in g'-order
__global__ void k_prep_wr2(const void* __restrict__ wr, const void* __restrict__ wk,
                           const void* __restrict__ bk, const void* __restrict__ br,
                           u16* __restrict__ wrP2, float* __restrict__ biasC,
                           float* __restrict__ wlC, const int* __restrict__ flagp) {
  int isbf = *flagp;
  int i0 = blockIdx.x * blockDim.x + threadIdx.x;
  int stride = gridDim.x * blockDim.x;
  for (int j = i0; j < 1552 * 384; j += stride) {
    int gp = j / 384, k = j - gp * 384;
    int g = gperm(gp);
    wrP2[j] = f2bf(ldf(wr, (size_t)g * 385 + k, isbf));
  }
  for (int gp = i0; gp < 1552; gp += stride) {
    int g = gperm(gp);
    biasC[gp] = ldf(bk, g, isbf) + ldf(br, g, isbf);
    wlC[gp] = ldf(wk, (size_t)g * 8193 + 8192, isbf) + ldf(wr, g * 385 + 384, isbf);
  }
}

__global__ void k_repack_wc(const void* __restrict__ wc, u16* __restrict__ wcp,
                            const int* __restrict__ flagp) {
  int isbf = *flagp;
  int i0 = blockIdx.x * blockDim.x + threadIdx.x;
  int stride = gridDim.x * blockDim.x;
  for (int j = i0; j < 384 * 3840; j += stride) {
    int o = j / 3840;
    int r = j - o * 3840;
    int k = r / 384;
    int h = r - k * 384;
    wcp[j] = f2bf(ldf(wc, (o * 384 + h) * 10 + k, isbf));  // [o][h][k]->[o][k][h]
  }
}

// canonical fp32: [vt 12800][Ws 24576][bs 64][Wrs 24576][brs 384][bc 384]
//                 [Wo 49152][bo 128]  (total 112064 floats)
__global__ void k_cvt_smalls(const void* vt, const void* Ws, const void* bs,
                             const void* Wrs, const void* brs, const void* bc,
                             const void* Wo, const void* bo,
                             float* __restrict__ dst, const int* __restrict__ flagp) {
  int isbf = *flagp;
  int i = blockIdx.x * blockDim.x + threadIdx.x;
  int stride = gridDim.x * blockDim.x;
  for (; i < 112064; i += stride) {
    float v;
    if (i < 12800) v = ldf(vt, i, isbf);
    else if (i < 37376) v = ldf(Ws, i - 12800, isbf);
    else if (i < 37440) v = ldf(bs, i - 37376, isbf);
    else if (i < 62016) v = ldf(Wrs, i - 37440, isbf);
    else if (i < 62400) v = ldf(brs, i - 62016, isbf);
    else if (i < 62784) v = ldf(bc, i - 62400, isbf);
    else if (i < 111936) v = ldf(Wo, i - 62784, isbf);
    else v = ldf(bo, i - 111936, isbf);
    dst[i] = v;
  }
}

__global__ void k_zero(float* __restrict__ p, int n) {
  int i = blockIdx.x * blockDim.x + threadIdx.x;
  int stride = gridDim.x * blockDim.x;
  for (; i < n; i += stride) p[i] = 0.f;
}

// ------------------------- PH1: gathered GEMM ------------------------------
// Linear grid 1300, panel-clustered XCD mapping (xcd=lin&7). Tile 128x128,
// BK=64 bf16. node_ids staged once to LDS (u16, stride 66 = bank-spread).
// Wk/bias/wl in g'-order; epilogue stores g'-contiguous.
__global__ __launch_bounds__(256) void k_gemm_xk(
    const int* __restrict__ node_ids, const u16* __restrict__ embB,
    const u16* __restrict__ wkp, const float* __restrict__ vtF,
    const float* __restrict__ biasC, const float* __restrict__ wlC,
    u16* __restrict__ xkb) {
  __shared__ alignas(16) u16 As[128 * 64];
  __shared__ alignas(16) u16 Bs[128 * 64];
  __shared__ alignas(16) u16 idS[128 * 66];  // stride 66: id reads bank-spread
  int tid = threadIdx.x;
  int lin = blockIdx.x;
  int xcd = lin & 7, slot = lin >> 3;
  int job = (xcd < 4) ? (xcd * 163 + slot) : (4 * 163 + (xcd - 4) * 162 + slot);
  int mb = job % 100, gb = job / 100;
  int m0 = mb * 128;
  int g0 = gb * 128;
  int tq = m0 >> 8, b0t = m0 & 255;
  int lane = tid & 63, w = tid >> 6;
  int wy = w >> 1, wx = w & 1;
  f32x4 acc[4][4];
#pragma unroll
  for (int i = 0; i < 4; ++i)
#pragma unroll
    for (int j = 0; j < 4; ++j) acc[i][j] = (f32x4){0.f, 0.f, 0.f, 0.f};

  // ---- stage node ids once (row-major int4 loads, u16 LDS store)
  {
    const int4* nb = (const int4*)(node_ids + ((size_t)b0t * 50 + tq) * 64);
    for (int i = tid; i < 2048; i += 256) {
      int row = i >> 4, c4 = i & 15;
      int4 v = nb[(size_t)row * 800 + c4];  // row stride 50*64/4 = 800 int4
      u16* d = idS + row * 66 + c4 * 4;
      d[0] = (u16)v.x; d[1] = (u16)v.y; d[2] = (u16)v.z; d[3] = (u16)v.w;
    }
  }

  int l15 = lane & 15, lq = lane >> 4;
  int lr = lane >> 3, lc = lane & 7;
  int swc = (lc ^ lr) * 8;
  int cRd = (lq ^ (l15 & 7)) * 8;

  for (int kt = 0; kt < 128; ++kt) {
    __syncthreads();
#pragma unroll
    for (int c = 0; c < 4; ++c) {
      int chunk = w * 4 + c;
      int r = chunk * 8 + lr;
      int id = (int)idS[r * 66 + (kt >> 1)];
      const u16* gp = embB + (size_t)id * 128 + (kt & 1) * 64 + swc;
      u16* lp = As + chunk * 512 + lane * 8;
      GLL(gp, lp);
    }
#pragma unroll
    for (int c = 0; c < 4; ++c) {
      int chunk = w * 4 + c;
      int r = chunk * 8 + lr;
      const u16* gp = wkp + (size_t)(g0 + r) * 8192 + (size_t)kt * 64 + swc;
      u16* lp = Bs + chunk * 512 + lane * 8;
      GLL(gp, lp);
    }
    __syncthreads();
    const u16* Ab = As + (wy * 64 + l15) * 64;
    const u16* Bb = Bs + (wx * 64 + l15) * 64;
#pragma unroll
    for (int ks = 0; ks < 2; ++ks) {
      int co = cRd ^ (ks * 32);
      bf16x8 av[4], bv[4];
#pragma unroll
      for (int i = 0; i < 4; ++i) av[i] = *(const bf16x8*)(Ab + i * 1024 + co);
#pragma unroll
      for (int j = 0; j < 4; ++j) bv[j] = *(const bf16x8*)(Bb + j * 1024 + co);
#pragma unroll
      for (int i = 0; i < 4; ++i)
#pragma unroll
        for (int j = 0; j < 4; ++j)
          acc[i][j] =
              __builtin_amdgcn_mfma_f32_16x16x32_bf16(av[i], bv[j], acc[i][j], 0, 0, 0);
    }
  }
  float vt[4][4];
#pragma unroll
  for (int i = 0; i < 4; ++i)
#pragma unroll
    for (int p = 0; p < 4; ++p)
      vt[i][p] = vtF[(size_t)(b0t + wy * 64 + i * 16 + lq * 4 + p) * 50 + tq];
#pragma unroll
  for (int j = 0; j < 4; ++j) {
    int gcol = g0 + wx * 64 + j * 16 + l15;
    if (gcol < 1552) {
      float bC = biasC[gcol], wC = wlC[gcol];
#pragma unroll
      for (int i = 0; i < 4; ++i)
#pragma unroll
        for (int p = 0; p < 4; ++p) {
          int row = wy * 64 + i * 16 + lq * 4 + p;
          xkb[(size_t)(m0 + row) * 1552 + gcol] =
              f2bf(acc[i][j][p] + bC + vt[i][p] * wC);
        }
    }
  }
}

// ------------------------- PH2: persistent LLC-coherent scan ---------------
// 192 blocks (1/CU via 128KB LDS -> all co-resident), 512 thr = 8 waves.
// Block (gs,bg): Wr slice (144 rows: 16 fm/im + 128 gate) LDS-RESIDENT,
// loaded once. Per step: h staged via RELAXED agent atomic u32 loads (LLC);
// MFMA A=WrS,B=hS; lane's D-frag = 4 gate pre-acts of (b=b0+l15,
// h=gs*32+wv*4+lq); gates in-register (creg f32/lane); h bf16-pairs stored
// via relaxed agent atomics; vmcnt(0) -> 12-block monotonic counter barrier
// (RELAXED ONLY: no acquire/release -> no buffer_wbl2/inv cache flushes).
__global__ __launch_bounds__(512) void k_scan5(
    const u16* __restrict__ xkb,        // [50][256][1552] bf16, permuted g'
    const u16* __restrict__ wrP2,       // [1552][384] bf16, permuted g'
    float* __restrict__ hbuf,           // [50][256][384] f32
    float* __restrict__ dbuf,           // [50][256] f32
    unsigned int* __restrict__ hx,      // [2][256][192] u32 packed bf16, zeroed
    int* __restrict__ barCnt) {         // [16] zeroed
  __shared__ alignas(16) u16 WrS[144 * 392];   // 112896B
  __shared__ alignas(16) u16 hS[16 * 392];     // 12544B
  __shared__ alignas(16) float fmTile[16 * 17];
  __shared__ float fmS[16][8], imS[16][8];

  int tid = threadIdx.x;
  int L = blockIdx.x;
  int xcd = L & 7, kk = L >> 3;
  int hi = (kk >= 12) ? 1 : 0;
  int bg = (xcd << 1) | hi;   // b-group [0,16)
  int gs = kk - 12 * hi;      // g-slice [0,12)
  int b0 = bg * 16;
  int wv = tid >> 6, lane = tid & 63, l15 = lane & 15, lq = lane >> 4;

  // one-time: Wr slab -> LDS (rows 0..15 fm/im, 16..143 gate rows of slice)
  for (int idx = tid; idx < 144 * 48; idx += 512) {
    int r = idx / 48, c = idx - r * 48;
    int gr = (r < 16) ? r : (16 + gs * 128 + (r - 16));
    *(uint4*)(WrS + r * 392 + c * 8) =
        *(const uint4*)(wrP2 + (size_t)gr * 384 + c * 8);
  }

  int hmy = gs * 32 + wv * 4 + lq;
  int lmy = hmy / 48;
  int bmy = b0 + l15;
  float creg = 0.f;

  const u16* arow_g = WrS + (16 + wv * 16 + l15) * 392 + lq * 8;
  const u16* arow_f = WrS + l15 * 392 + lq * 8;
  const u16* brow = hS + l15 * 392 + lq * 8;
  __syncthreads();

  for (int t = 0; t < 50; ++t) {
    // ---- xk prefetch (plain loads; xkb is read-only, stream-ordered)
    uint2 xkg = *(const uint2*)(xkb + ((size_t)t * 256 + bmy) * 1552 + 16 +
                                gs * 128 + wv * 16 + lq * 4);
    uint4 xksm = (uint4){0u, 0u, 0u, 0u};
    if (tid < 32)
      xksm = *(const uint4*)(xkb + ((size_t)t * 256 + b0 + (tid & 15)) * 1552 +
                             ((tid < 16) ? 0 : 8));

    // ---- stage h_{t-1} from hx[t&1] via relaxed agent atomic loads (LLC)
    {
      const unsigned int* hxin = hx + (size_t)(t & 1) * 49152 + (size_t)b0 * 192;
#pragma unroll
      for (int k2 = 0; k2 < 6; ++k2) {
        int j = tid + k2 * 512;
        int r = j / 192, c = j - r * 192;
        unsigned int v = __hip_atomic_load(&hxin[r * 192 + c], __ATOMIC_RELAXED,
                                           __HIP_MEMORY_SCOPE_AGENT);
        *(unsigned int*)((char*)hS + r * 784 + c * 4) = v;
      }
    }
    __syncthreads();

    // ---- B-frags (h_{t-1})
    bf16x8 hb[12];
#pragma unroll
    for (int ks = 0; ks < 12; ++ks)
      hb[ks] = *(const bf16x8*)(brow + ks * 32);

    // ---- MFMA: gate tile (all waves) + fm/im tile (wave 0)
    f32x4 accg = (f32x4){0.f, 0.f, 0.f, 0.f};
    f32x4 accf = (f32x4){0.f, 0.f, 0.f, 0.f};
#pragma unroll
    for (int ks = 0; ks < 12; ++ks) {
      bf16x8 ag = *(const bf16x8*)(arow_g + ks * 32);
      accg = __builtin_amdgcn_mfma_f32_16x16x32_bf16(ag, hb[ks], accg, 0, 0, 0);
      if (wv == 0) {
        bf16x8 a0 = *(const bf16x8*)(arow_f + ks * 32);
        accf = __builtin_amdgcn_mfma_f32_16x16x32_bf16(a0, hb[ks], accf, 0, 0, 0);
      }
    }
    if (wv == 0) {
#pragma unroll
      for (int p = 0; p < 4; ++p) fmTile[(lq * 4 + p) * 17 + l15] = accf[p];
    }
    __syncthreads();

    // ---- fm/im softmax (fm: tid<16, im: tid 16..31)
    if (tid < 32) {
      int r = tid & 15;
      const u16* xs = (const u16*)&xksm;
      float z[8], m = -1e30f;
#pragma unroll
      for (int j = 0; j < 8; ++j) {
        int jj = (tid < 16) ? j : (8 + j);
        z[j] = fmTile[jj * 17 + r] + bf2f(xs[j]);
        m = fmaxf(m, z[j]);
      }
      float s = 0.f;
#pragma unroll
      for (int j = 0; j < 8; ++j) { z[j] = __expf(z[j] - m); s += z[j]; }
      float inv = 1.f / s;
      if (tid < 16) {
        float run = 0.f, fsum = 0.f;
#pragma unroll
        for (int j = 0; j < 8; ++j) { run += z[j] * inv; fmS[r][j] = run; fsum += run; }
        if (gs == 0) dbuf[(size_t)t * 256 + b0 + r] = 1.f - fsum * 0.125f;
      } else {
        float run = 0.f;
#pragma unroll
        for (int j = 7; j >= 0; --j) { run += z[j] * inv; imS[r][j] = run; }
      }
    }
    __syncthreads();

    // ---- gates, fully in-register (one (b,h) cell per lane)
    {
      const u16* xg = (const u16*)&xkg;
      float x0 = accg[0] + bf2f(xg[0]);
      float x1 = accg[1] + bf2f(xg[1]);
      float x2 = accg[2] + bf2f(xg[2]);
      float x3 = accg[3] + bf2f(xg[3]);
      float fg = sigf(x0), ig = sigf(x1), og = sigf(x2), ci = tanhf_(x3);
      float fm = fmS[l15][lmy], im = imS[l15][lmy];
      float ov = fm * im;
      float cn = ov * (fg * creg + ig * ci) + (fm - ov) * creg + (im - ov) * ci;
      float hn = og * tanhf_(cn);
      creg = cn;
      hbuf[((size_t)t * 256 + bmy) * 384 + hmy] = hn;
      if (t != 49) {
        unsigned int v = (unsigned int)f2bf(hn);
        unsigned int up = __shfl_down(v, 16);
        if ((lq & 1) == 0) {
          unsigned int packed = v | (up << 16);
          __hip_atomic_store(
              &hx[(size_t)((t + 1) & 1) * 49152 + (size_t)bmy * 192 + gs * 16 +
                  wv * 2 + (lq >> 1)],
              packed, __ATOMIC_RELAXED, __HIP_MEMORY_SCOPE_AGENT);
        }
      }
    }

    // ---- 12-block group barrier (relaxed-only; skip after last step)
    if (t != 49) {
      asm volatile("s_waitcnt vmcnt(0)" ::: "memory");
      __syncthreads();
      if (tid == 0) {
        __hip_atomic_fetch_add(&barCnt[bg], 1, __ATOMIC_RELAXED,
                               __HIP_MEMORY_SCOPE_AGENT);
        while (__hip_atomic_load(&barCnt[bg], __ATOMIC_RELAXED,
                                 __HIP_MEMORY_SCOPE_AGENT) < 12 * (t + 1)) {
          __builtin_amdgcn_s_sleep(1);
        }
      }
      __syncthreads();
    }
  }
}

// ------------------------- PH3: final (theme/conv/out) ---------------------
__global__ __launch_bounds__(384) void k_final(
    const float* __restrict__ hbuf, const float* __restrict__ dbuf,
    const unsigned char* __restrict__ am, const float* __restrict__ smalls,
    const u16* __restrict__ wcp, float* __restrict__ out) {
  const float* WsF = smalls + 12800;
  const float* bsF = smalls + 37376;
  const float* WrsF = smalls + 37440;
  const float* brsF = smalls + 62016;
  const float* bcF = smalls + 62400;
  const float* WoF = smalls + 62784;
  const float* boF = smalls + 111936;
  __shared__ alignas(16) float lh2[10][384];
  __shared__ alignas(16) float ti[384];
  __shared__ alignas(16) float us[64];
  __shared__ alignas(16) float rnnS[384];
  __shared__ alignas(16) float hlastS[384];
  __shared__ float ldS[10];
  __shared__ int npad[50];
  __shared__ int lastS;
  int tid = threadIdx.x;
  int b = blockIdx.x;

  if (tid < 50) {
    const unsigned char* mr = am + ((size_t)b * 50 + tid) * 64;
    int all1 = 1;
    for (int q = 0; q < 64; ++q) all1 &= (mr[q] != 0);
    npad[tid] = all1 ? 0 : 1;
  }
  __syncthreads();
  if (tid == 0) {
    int c = 0;
    for (int v = 0; v < 50; ++v) c += npad[v];
    int lv = c - 1;
    int last = lv < 0 ? 0 : lv;
    lastS = last;
    float cum = 0.f, cv[10];
    for (int k = 0; k < 10; ++k) {
      int s = last - 9 + k;
      float dk = (s >= 0) ? dbuf[(size_t)s * 256 + b] : 0.f;
      cum += dk;
      cv[k] = cum;
    }
    float m = cv[0];
    for (int k = 1; k < 10; ++k) m = fmaxf(m, cv[k]);
    float ssum = 0.f, ee[10];
    for (int k = 0; k < 10; ++k) { ee[k] = __expf(cv[k] - m); ssum += ee[k]; }
    float inv = 1.f / ssum;
    for (int k = 0; k < 10; ++k) ldS[k] = ee[k] * inv;
  }
  __syncthreads();
  {  // local_h, theme input, h_last
    int h = tid;
    int last = lastS;
    float ssum = 0.f;
    for (int k = 0; k < 10; ++k) {
      int s = last - 9 + k;
      float hv = (s >= 0) ? hbuf[((size_t)s * 256 + b) * 384 + h] : 0.f;
      float v = hv * ldS[k];
      lh2[k][h] = v;
      ssum += v;
    }
    ti[h] = ssum * 0.1f;
    hlastS[h] = hbuf[((size_t)last * 256 + b) * 384 + h];
  }
  __syncthreads();
  if (tid < 64) {  // u = relu(ti @ Ws^T + bs)
    float a = bsF[tid];
    const float* wr = WsF + (size_t)tid * 384;
    for (int h = 0; h < 384; ++h) a += wr[h] * ti[h];
    us[tid] = fmaxf(a, 0.f);
  }
  __syncthreads();
  {  // theme = sigmoid(u @ Wrs^T + brs); conv; rnn = theme*conv + h_last
    int o = tid;
    float th = brsF[o];
    const float* wr = WrsF + (size_t)o * 64;
    for (int k = 0; k < 64; ++k) th += wr[k] * us[k];
    th = sigf(th);
    float cacc = bcF[o];
    for (int k = 0; k < 10; ++k) {
      const u16* wrow = wcp + ((size_t)o * 10 + k) * 384;
      const float* lrow = lh2[k];
      for (int h8 = 0; h8 < 48; ++h8) cacc += dot8_bf(wrow + h8 * 8, lrow + h8 * 8);
    }
    rnnS[o] = th * cacc + hlastS[o];
  }
  __syncthreads();
  if (tid < 128) {  // out = rnn @ Wo^T + bo, fp32
    float a = boF[tid];
    const float* wr = WoF + (size_t)tid * 384;
    for (int h = 0; h < 384; ++h) a += wr[h] * rnnS[h];
    out[(size_t)b * 128 + tid] = a;
  }
}

// ------------------------- launch ------------------------------------------
extern "C" void kernel_launch(void* const* d_in, const int* in_sizes, int n_in,
                              void* d_out, int out_size, void* d_ws, size_t ws_size,
                              hipStream_t stream) {
  const int* node_ids = (const int*)d_in[0];
  const void* vtR = d_in[3];
  const unsigned char* am = (const unsigned char*)d_in[5];
  const void* embR = d_in[6];
  const void* WkR = d_in[7];
  const void* bkR = d_in[8];
  const void* WrR = d_in[9];
  const void* brR = d_in[10];
  const void* WsR = d_in[11];
  const void* bsR = d_in[12];
  const void* WrsR = d_in[13];
  const void* brsR = d_in[14];
  const void* WcR = d_in[15];
  const void* bcR = d_in[16];
  const void* WoR = d_in[17];
  const void* boR = d_in[18];
  (void)in_sizes; (void)n_in; (void)out_size; (void)ws_size;

  char* ws = (char*)d_ws;
  size_t off = 0;
  auto alloc = [&](size_t bytes) {
    void* p = ws + off;
    off = (off + bytes + 255) & ~(size_t)255;
    return p;
  };
  int* flagp = (int*)alloc(4);
  u16* embB = (u16*)alloc((size_t)10001 * 128 * 2);      // 2.56MB
  u16* WkP = (u16*)alloc((size_t)1664 * 8192 * 2);       // 27.3MB g'-ordered
  u16* WrP2 = (u16*)alloc((size_t)1552 * 384 * 2);       // 1.19MB bf16 permuted
  float* biasC = (float*)alloc(1552 * 4);
  float* wlC = (float*)alloc(1552 * 4);
  float* smalls = (float*)alloc((size_t)112064 * 4);
  u16* XKb = (u16*)alloc((size_t)12800 * 1552 * 2);      // 39.7MB [t][b][g']
  u16* WcP = (u16*)alloc((size_t)384 * 3840 * 2);        // 2.9MB
  float* Hbuf = (float*)alloc((size_t)50 * 256 * 384 * 4);  // 19.7MB
  float* Dbuf = (float*)alloc((size_t)50 * 256 * 4);
  unsigned int* Hx = (unsigned int*)alloc((size_t)2 * 256 * 192 * 4);  // 393KB
  int* BarCnt = (int*)alloc(16 * 4);

  k_detect<<<dim3(1), dim3(64), 0, stream>>>((const unsigned int*)embR, flagp);
  k_cvt_emb<<<dim3(1024), dim3(256), 0, stream>>>(embR, embB, flagp);
  k_repack_wk<<<dim3(2048), dim3(256), 0, stream>>>(WkR, WkP, flagp);
  k_prep_wr2<<<dim3(512), dim3(256), 0, stream>>>(WrR, WkR, bkR, brR, WrP2, biasC,
                                                  wlC, flagp);
  k_repack_wc<<<dim3(512), dim3(256), 0, stream>>>(WcR, WcP, flagp);
  k_cvt_smalls<<<dim3(128), dim3(256), 0, stream>>>(vtR, WsR, bsR, WrsR, brsR,
                                                    bcR, WoR, boR, smalls, flagp);
  k_zero<<<dim3(96), dim3(256), 0, stream>>>((float*)Hx, 98304);
  k_zero<<<dim3(1), dim3(64), 0, stream>>>((float*)BarCnt, 16);

  k_gemm_xk<<<dim3(1300), dim3(256), 0, stream>>>(node_ids, embB, WkP, smalls,
                                                  biasC, wlC, XKb);

  k_scan5<<<dim3(192), dim3(512), 0, stream>>>(XKb, WrP2, Hbuf, Dbuf, Hx, BarCnt);

  k_final<<<dim3(256), dim3(384), 0, stream>>>(Hbuf, Dbuf, am, smalls, WcP,
                                               (float*)d_out);
}